// Round 1
// baseline (8454.329 us; speedup 1.0000x reference)
//
#include <hip/hip_runtime.h>
#include <math.h>

// ---------------- constants ----------------
constexpr int SLICE = 81 * 4096;   // per-channel (a,y,x) slab for 81-view stage
constexpr int VOL   = 9 * 4096;    // per-channel (d,y,x) slab for tower stage
constexpr float EPSB = 1e-5f;

// workspace offsets (in floats)
constexpr size_t OFF_HBUF  = 0;          // 16*SLICE = 5,308,416
constexpr size_t OFF_T16   = 5308416;    // 16*SLICE (also FEAT: first 8*SLICE)
constexpr size_t OFF_MASK  = 10616832;   // 81*4096
constexpr size_t OFF_INVM  = 10948608;   // 4096
constexpr size_t OFF_A     = 10952704;   // 648*160 = 103,680
constexpr size_t OFF_B0    = 11056384;   // 160*VOL = 5,898,240
constexpr size_t OFF_B1    = 16954624;
constexpr size_t OFF_B2    = 22852864;
constexpr size_t OFF_YM    = 28751104;   // 1440
constexpr size_t OFF_Y2    = 28752544;   // 1440
constexpr size_t OFF_SCORE = 28753984;   // 36864

__device__ __forceinline__ float lrelu_f(float v) { return v >= 0.f ? v : 0.1f * v; }

// ---------------- stage A: unshuffle + if0 conv + bn ----------------
__global__ __launch_bounds__(256) void k_if0(const float* __restrict__ x,
                                             const float* __restrict__ w0,
                                             const float* __restrict__ bn0,
                                             float* __restrict__ hb) {
  int a = blockIdx.x;                       // 0..80
  int p = blockIdx.y * 256 + threadIdx.x;   // 0..4095
  int y = p >> 6, xx = p & 63;
  int ai = a / 9, aj = a % 9;
  float v[3][3];
#pragma unroll
  for (int dy = 0; dy < 3; ++dy) {
    int gy = y + dy - 1;
#pragma unroll
    for (int dx = 0; dx < 3; ++dx) {
      int gx = xx + dx - 1;
      v[dy][dx] = (gy >= 0 && gy < 64 && gx >= 0 && gx < 64)
                      ? x[(ai * 64 + gy) * 576 + aj * 64 + gx] : 0.f;
    }
  }
#pragma unroll
  for (int c = 0; c < 16; ++c) {
    float acc = 0.f;
#pragma unroll
    for (int t = 0; t < 9; ++t) acc += w0[c * 9 + t] * v[t / 3][t % 3];
    float g = bn0[c], b = bn0[16 + c], m = bn0[32 + c], vv = bn0[48 + c];
    hb[(size_t)c * SLICE + a * 4096 + p] = (acc - m) * (g * rsqrtf(vv + EPSB)) + b;
  }
}

// ---------------- stage B: per-slice 3x3 conv (generic) ----------------
template <int CI, int CO, bool BIAS, bool BN, bool LRELU, bool RESADD>
__global__ __launch_bounds__(256) void k_cslice(const float* __restrict__ in,
                                                float* __restrict__ out,
                                                const float* __restrict__ w,
                                                const float* __restrict__ bias,
                                                const float* __restrict__ bnp) {
  __shared__ __align__(16) float in_t[CI][18][18];
  __shared__ __align__(16) float w_l[CI * 9 * CO];
  int a = blockIdx.x;
  int tile = blockIdx.y;
  int y0 = (tile >> 2) * 16, x0 = (tile & 3) * 16;
  int tid = threadIdx.x;
  for (int idx = tid; idx < CI * 324; idx += 256) {
    int ci = idx / 324, r = idx % 324;
    int yy = r / 18, xx = r % 18;
    int gy = y0 + yy - 1, gx = x0 + xx - 1;
    in_t[ci][yy][xx] = (gy >= 0 && gy < 64 && gx >= 0 && gx < 64)
                           ? in[(size_t)ci * SLICE + a * 4096 + gy * 64 + gx] : 0.f;
  }
  for (int idx = tid; idx < CI * 9 * CO; idx += 256) {
    int co = idx % CO;
    int rest = idx / CO;
    int ci = rest / 9, t = rest % 9;
    w_l[idx] = w[((size_t)co * CI + ci) * 9 + t];
  }
  __syncthreads();
  int ty = tid >> 4, tx = tid & 15;
  float acc[CO];
#pragma unroll
  for (int co = 0; co < CO; ++co) acc[co] = 0.f;
  for (int ci = 0; ci < CI; ++ci) {
#pragma unroll
    for (int t = 0; t < 9; ++t) {
      float v = in_t[ci][ty + t / 3][tx + t % 3];
      const float4* wr = (const float4*)&w_l[(ci * 9 + t) * CO];
#pragma unroll
      for (int q = 0; q < CO / 4; ++q) {
        float4 w4 = wr[q];
        acc[q * 4 + 0] += w4.x * v;
        acc[q * 4 + 1] += w4.y * v;
        acc[q * 4 + 2] += w4.z * v;
        acc[q * 4 + 3] += w4.w * v;
      }
    }
  }
  size_t po = (size_t)a * 4096 + (y0 + ty) * 64 + (x0 + tx);
#pragma unroll
  for (int co = 0; co < CO; ++co) {
    float val = acc[co];
    if (BIAS) val += bias[co];
    if (BN) {
      float g = bnp[co], b = bnp[CO + co], m = bnp[2 * CO + co], vv = bnp[3 * CO + co];
      val = (val - m) * (g * rsqrtf(vv + EPSB)) + b;
    }
    if (LRELU) val = lrelu_f(val);
    if (RESADD) out[(size_t)co * SLICE + po] += val;
    else        out[(size_t)co * SLICE + po] = val;
  }
}

// ---------------- mask generation ----------------
__device__ __forceinline__ float img_at(const float* __restrict__ x, int i, int j, int yy, int xx) {
  if (yy < 0 || yy >= 64 || xx < 0 || xx >= 64) return 0.f;
  return x[(i * 64 + yy) * 576 + j * 64 + xx];
}

__global__ __launch_bounds__(256) void k_mask(const float* __restrict__ x,
                                              const float* __restrict__ disp,
                                              float* __restrict__ mask,
                                              float* __restrict__ invm) {
  int p = blockIdx.x * 256 + threadIdx.x;  // 0..4095
  int y = p >> 6, xx = p & 63;
  float d = -disp[p];
  float ref = x[(4 * 64 + y) * 576 + 4 * 64 + xx];
  float ssum = 0.f;
  float xbase = (float)xx * (64.0f / 63.0f);
  float ybase = (float)y * (64.0f / 63.0f);
  for (int i = 0; i < 9; ++i) {
    float py = ybase + (float)(i - 4) * d - 0.5f;
    float y0f = floorf(py);
    float fy = py - y0f;
    int y0 = (int)y0f;
    for (int j = 0; j < 9; ++j) {
      float px = xbase + (float)(j - 4) * d - 0.5f;
      float x0f = floorf(px);
      float fx = px - x0f;
      int x0 = (int)x0f;
      float val = img_at(x, i, j, y0, x0) * (1.f - fx) * (1.f - fy)
                + img_at(x, i, j, y0, x0 + 1) * fx * (1.f - fy)
                + img_at(x, i, j, y0 + 1, x0) * (1.f - fx) * fy
                + img_at(x, i, j, y0 + 1, x0 + 1) * fx * fy;
      float diff = (i == 4 && j == 4) ? 0.f : fabsf(val - ref);
      float m = 1.f - diff;
      m = m * m;
      mask[(i * 9 + j) * 4096 + p] = m;
      ssum += m;
    }
  }
  invm[p] = 81.f / ssum;
}

// ---------------- A = sq_w (.) fuse_w  precompute ----------------
__global__ __launch_bounds__(256) void k_A(const float* __restrict__ sq_w,
                                           const float* __restrict__ fuse_w,
                                           float* __restrict__ A) {
  int guv = blockIdx.x;            // g*81+uv, 0..647
  int g = guv / 81, uv = guv % 81;
  int o = threadIdx.x;
  if (o >= 160) return;
  float acc = 0.f;
  for (int o2 = 0; o2 < 64; ++o2)
    acc += sq_w[(size_t)o * 512 + g * 64 + o2] * fuse_w[(size_t)(g * 64 + o2) * 81 + uv];
  A[(size_t)guv * 160 + o] = acc;
}

// ---------------- fused cost volume + squeeze (bn+lrelu) ----------------
__global__ __launch_bounds__(256) void k_costsq(const float* __restrict__ feat,
                                                const float* __restrict__ mask,
                                                const float* __restrict__ invm,
                                                const float* __restrict__ A,
                                                const float* __restrict__ sq_bn,
                                                float* __restrict__ out) {
  __shared__ float s[8 * 81 * 16];
  int xt = blockIdx.x;     // 0..3
  int y  = blockIdx.y;     // 0..63
  int dI = blockIdx.z;     // 0..8
  int dd = dI - 4;
  int x0 = xt * 16;
  int tid = threadIdx.x;
  for (int idx = tid; idx < 8 * 81 * 16; idx += 256) {
    int g = idx / (81 * 16);
    int r = idx % (81 * 16);
    int uv = r / 16;
    int xl = r & 15;
    int u = uv / 9, v = uv % 9;
    int ys = y + (4 - u) * dd;
    int xs = x0 + xl + (4 - v) * dd;
    float f = (ys >= 0 && ys < 64 && xs >= 0 && xs < 64)
                  ? feat[(size_t)g * SLICE + uv * 4096 + ys * 64 + xs] : 0.f;
    s[idx] = f * mask[uv * 4096 + y * 64 + x0 + xl];
  }
  __syncthreads();
  int xl = tid & 15, ob = tid >> 4;  // ob 0..15
  float acc[10];
#pragma unroll
  for (int k = 0; k < 10; ++k) acc[k] = 0.f;
  for (int g = 0; g < 8; ++g) {
    for (int uv = 0; uv < 81; ++uv) {
      float sv = s[(g * 81 + uv) * 16 + xl];
      const float* Ar = &A[(size_t)(g * 81 + uv) * 160];
#pragma unroll
      for (int k = 0; k < 10; ++k) acc[k] += Ar[ob + 16 * k] * sv;
    }
  }
  float im = invm[y * 64 + x0 + xl];
#pragma unroll
  for (int k = 0; k < 10; ++k) {
    int o = ob + 16 * k;
    float val = acc[k] * im;
    float g = sq_bn[o], b = sq_bn[160 + o], m = sq_bn[320 + o], vv = sq_bn[480 + o];
    val = (val - m) * (g * rsqrtf(vv + EPSB)) + b;
    val = lrelu_f(val);
    out[(size_t)o * VOL + dI * 4096 + y * 64 + x0 + xl] = val;
  }
}

// ---------------- tower 3x3x3 conv, 160->160, bn (+optional lrelu) ----------------
template <bool LRELU>
__global__ __launch_bounds__(256) void k_conv3(const float* __restrict__ in,
                                               float* __restrict__ out,
                                               const float* __restrict__ w,
                                               const float* __restrict__ bnp) {
  __shared__ __align__(16) float in_l[4][3][10][66];
  __shared__ __align__(16) float w_l[4 * 27 * 16];
  int yt = blockIdx.x;   // 0..7  (8 rows each)
  int z  = blockIdx.y;   // 0..8
  int og = blockIdx.z;   // 0..9
  int y0 = yt * 8;
  int tid = threadIdx.x;
  int x  = tid & 31;     // handles x and x+32
  int yl = tid >> 5;     // 0..7
  float acc[32];
#pragma unroll
  for (int q = 0; q < 32; ++q) acc[q] = 0.f;

#pragma unroll 1
  for (int cc = 0; cc < 160; cc += 4) {
    for (int idx = tid; idx < 4 * 1980; idx += 256) {
      int ci = idx / 1980;
      int r = idx - ci * 1980;
      int zz = r / 660; r -= zz * 660;
      int yy = r / 66;
      int xx = r - yy * 66;
      int gz = z + zz - 1, gy = y0 + yy - 1, gx = xx - 1;
      float val = 0.f;
      if (gz >= 0 && gz < 9 && gy >= 0 && gy < 64 && gx >= 0 && gx < 64)
        val = in[(size_t)(cc + ci) * VOL + gz * 4096 + gy * 64 + gx];
      in_l[ci][zz][yy][xx] = val;
    }
    for (int idx = tid; idx < 4 * 27 * 16; idx += 256) {
      int o = idx & 15;
      int rest = idx >> 4;
      int ci = rest / 27, t = rest - ci * 27;
      w_l[idx] = w[((size_t)(og * 16 + o) * 160 + cc + ci) * 27 + t];
    }
    __syncthreads();
#pragma unroll
    for (int ci = 0; ci < 4; ++ci) {
#pragma unroll
      for (int dz = 0; dz < 3; ++dz) {
#pragma unroll
        for (int dy = 0; dy < 3; ++dy) {
          const float* row = &in_l[ci][dz][yl + dy][0];
#pragma unroll
          for (int dx = 0; dx < 3; ++dx) {
            float v0 = row[x + dx];
            float v1 = row[x + 32 + dx];
            const float4* wr = (const float4*)&w_l[(ci * 27 + (dz * 3 + dy) * 3 + dx) * 16];
#pragma unroll
            for (int q = 0; q < 4; ++q) {
              float4 w4 = wr[q];
              acc[q * 4 + 0] += w4.x * v0;
              acc[q * 4 + 1] += w4.y * v0;
              acc[q * 4 + 2] += w4.z * v0;
              acc[q * 4 + 3] += w4.w * v0;
              acc[16 + q * 4 + 0] += w4.x * v1;
              acc[16 + q * 4 + 1] += w4.y * v1;
              acc[16 + q * 4 + 2] += w4.z * v1;
              acc[16 + q * 4 + 3] += w4.w * v1;
            }
          }
        }
      }
    }
    __syncthreads();
  }
  int y = y0 + yl;
#pragma unroll
  for (int half = 0; half < 2; ++half) {
    int xg = x + 32 * half;
#pragma unroll
    for (int o = 0; o < 16; ++o) {
      int co = og * 16 + o;
      float val = acc[half * 16 + o];
      float g = bnp[co], b = bnp[160 + co], m = bnp[320 + co], vv = bnp[480 + co];
      val = (val - m) * (g * rsqrtf(vv + EPSB)) + b;
      if (LRELU) val = lrelu_f(val);
      out[(size_t)co * VOL + z * 4096 + y * 64 + xg] = val;
    }
  }
}

// ---------------- c4: 160 -> 1 conv, no bn ----------------
__global__ __launch_bounds__(256) void k_c4(const float* __restrict__ in,
                                            const float* __restrict__ w,
                                            float* __restrict__ score) {
  int p = blockIdx.x * 256 + threadIdx.x;  // < 36864
  int z = p / 4096;
  int r = p % 4096;
  int y = r / 64, x = r % 64;
  float acc = 0.f;
  for (int ci = 0; ci < 160; ++ci) {
    const float* wp = w + ci * 27;
    const float* ip = in + (size_t)ci * VOL;
#pragma unroll
    for (int dz = 0; dz < 3; ++dz) {
      int gz = z + dz - 1;
      if (gz < 0 || gz >= 9) continue;
#pragma unroll
      for (int dy = 0; dy < 3; ++dy) {
        int gy = y + dy - 1;
        if (gy < 0 || gy >= 64) continue;
#pragma unroll
        for (int dx = 0; dx < 3; ++dx) {
          int gx = x + dx - 1;
          if (gx < 0 || gx >= 64) continue;
          acc += wp[dz * 9 + dy * 3 + dx] * ip[gz * 4096 + gy * 64 + gx];
        }
      }
    }
  }
  score[p] = acc;
}

// ---------------- channel-attention helpers ----------------
__global__ __launch_bounds__(256) void k_mean(const float* __restrict__ in,
                                              float* __restrict__ ym) {
  __shared__ float red[256];
  int cz = blockIdx.x;  // 0..1439
  const float* p = in + (size_t)cz * 4096;
  float s = 0.f;
  for (int i = threadIdx.x; i < 4096; i += 256) s += p[i];
  red[threadIdx.x] = s;
  __syncthreads();
  for (int st = 128; st > 0; st >>= 1) {
    if (threadIdx.x < st) red[threadIdx.x] += red[threadIdx.x + st];
    __syncthreads();
  }
  if (threadIdx.x == 0) ym[cz] = red[0] * (1.f / 4096.f);
}

__global__ __launch_bounds__(256) void k_ca(const float* __restrict__ ym,
                                            const float* __restrict__ w1,
                                            const float* __restrict__ b1,
                                            const float* __restrict__ bn1,
                                            const float* __restrict__ w2,
                                            const float* __restrict__ b2,
                                            const float* __restrict__ bn2,
                                            float* __restrict__ y2) {
  __shared__ float yml[1440];
  __shared__ float yy[90];
  for (int i = threadIdx.x; i < 1440; i += 256) yml[i] = ym[i];
  __syncthreads();
  if (threadIdx.x < 90) {
    int c = threadIdx.x / 9, z = threadIdx.x % 9;
    float acc = b1[c];
    for (int ci = 0; ci < 160; ++ci) acc += w1[c * 160 + ci] * yml[ci * 9 + z];
    float g = bn1[c], b = bn1[10 + c], m = bn1[20 + c], vv = bn1[30 + c];
    acc = (acc - m) * (g * rsqrtf(vv + EPSB)) + b;
    yy[threadIdx.x] = lrelu_f(acc);
  }
  __syncthreads();
  for (int i = threadIdx.x; i < 1440; i += 256) {
    int c = i / 9, z = i % 9;
    float acc = b2[c];
#pragma unroll
    for (int k = 0; k < 10; ++k) acc += w2[c * 10 + k] * yy[k * 9 + z];
    float g = bn2[c], b = bn2[160 + c], m = bn2[320 + c], vv = bn2[480 + c];
    acc = (acc - m) * (g * rsqrtf(vv + EPSB)) + b;
    y2[i] = 1.f / (1.f + expf(-acc));
  }
}

__global__ __launch_bounds__(256) void k_sadd(float* __restrict__ buf,
                                              const float* __restrict__ t,
                                              const float* __restrict__ y2) {
  int i = blockIdx.x * 256 + threadIdx.x;  // < 5,898,240
  int cz = i >> 12;
  buf[i] += t[i] * y2[cz];
}

// ---------------- softmax + expectation ----------------
__global__ __launch_bounds__(256) void k_out(const float* __restrict__ score,
                                             float* __restrict__ out) {
  int p = blockIdx.x * 256 + threadIdx.x;  // < 4096
  float v[9];
  float mx = -1e30f;
#pragma unroll
  for (int z = 0; z < 9; ++z) {
    v[z] = score[z * 4096 + p];
    mx = fmaxf(mx, v[z]);
  }
  float s = 0.f, r = 0.f;
#pragma unroll
  for (int z = 0; z < 9; ++z) {
    float e = expf(v[z] - mx);
    s += e;
    r += e * (float)(z - 4);
  }
  out[p] = r / s;
}

// ---------------- launch ----------------
extern "C" void kernel_launch(void* const* d_in, const int* in_sizes, int n_in,
                              void* d_out, int out_size, void* d_ws, size_t ws_size,
                              hipStream_t stream) {
  const float* X      = (const float*)d_in[0];
  const float* disp   = (const float*)d_in[1];
  const float* if_w0  = (const float*)d_in[2];
  const float* if_bn0 = (const float*)d_in[3];
  const float* resb_w = (const float*)d_in[4];
  const float* resb_b = (const float*)d_in[5];
  const float* resb_bn= (const float*)d_in[6];
  const float* if_w1  = (const float*)d_in[7];
  const float* if_bn1 = (const float*)d_in[8];
  const float* if_w2  = (const float*)d_in[9];
  const float* if_bn2 = (const float*)d_in[10];
  const float* last_w = (const float*)d_in[11];
  const float* fuse_w = (const float*)d_in[12];
  const float* sq_w   = (const float*)d_in[13];
  const float* sq_bn  = (const float*)d_in[14];
  const float* c1_w   = (const float*)d_in[15];
  const float* c1_bn  = (const float*)d_in[16];
  const float* c2_w   = (const float*)d_in[17];
  const float* c2_bn  = (const float*)d_in[18];
  const float* c3_w   = (const float*)d_in[19];
  const float* c3_bn  = (const float*)d_in[20];
  const float* c4_w   = (const float*)d_in[21];
  const float* r3_w   = (const float*)d_in[22];
  const float* r3_bn  = (const float*)d_in[23];
  const float* ca_w1  = (const float*)d_in[24];
  const float* ca_b1  = (const float*)d_in[25];
  const float* ca_bn1 = (const float*)d_in[26];
  const float* ca_w2  = (const float*)d_in[27];
  const float* ca_b2  = (const float*)d_in[28];
  const float* ca_bn2 = (const float*)d_in[29];

  float* ws   = (float*)d_ws;
  float* HB   = ws + OFF_HBUF;
  float* T16  = ws + OFF_T16;
  float* FEAT = T16;                 // 8-channel result reuses T16 region
  float* MASK = ws + OFF_MASK;
  float* INVM = ws + OFF_INVM;
  float* Abuf = ws + OFF_A;
  float* B0   = ws + OFF_B0;
  float* B1   = ws + OFF_B1;
  float* B2   = ws + OFF_B2;
  float* YM   = ws + OFF_YM;
  float* Y2   = ws + OFF_Y2;
  float* SC   = ws + OFF_SCORE;

  // stage A
  k_if0<<<dim3(81, 16), 256, 0, stream>>>(X, if_w0, if_bn0, HB);

  // stage B: 8 residual blocks, then if1/if2/last
  for (int i = 0; i < 8; ++i) {
    k_cslice<16, 16, true, true, true, false><<<dim3(81, 16), 256, 0, stream>>>(
        HB, T16, resb_w + i * 4608, resb_b + i * 32, resb_bn + i * 128);
    k_cslice<16, 16, true, true, false, true><<<dim3(81, 16), 256, 0, stream>>>(
        T16, HB, resb_w + i * 4608 + 2304, resb_b + i * 32 + 16, resb_bn + i * 128 + 64);
  }
  k_cslice<16, 16, false, true, true, false><<<dim3(81, 16), 256, 0, stream>>>(
      HB, T16, if_w1, nullptr, if_bn1);
  k_cslice<16, 8, false, true, true, false><<<dim3(81, 16), 256, 0, stream>>>(
      T16, HB, if_w2, nullptr, if_bn2);
  k_cslice<8, 8, false, false, false, false><<<dim3(81, 16), 256, 0, stream>>>(
      HB, FEAT, last_w, nullptr, nullptr);

  // mask + A + fused cost/squeeze
  k_mask<<<16, 256, 0, stream>>>(X, disp, MASK, INVM);
  k_A<<<648, 256, 0, stream>>>(sq_w, fuse_w, Abuf);
  k_costsq<<<dim3(4, 64, 9), 256, 0, stream>>>(FEAT, MASK, INVM, Abuf, sq_bn, B0);

  // tower
  k_conv3<true><<<dim3(8, 9, 10), 256, 0, stream>>>(B0, B1, c1_w, c1_bn);
  k_conv3<true><<<dim3(8, 9, 10), 256, 0, stream>>>(B1, B0, c2_w, c2_bn);
  for (int i = 0; i < 2; ++i) {
    k_conv3<true><<<dim3(8, 9, 10), 256, 0, stream>>>(
        B0, B1, r3_w + (size_t)i * 2 * 691200, r3_bn + i * 1280);
    k_conv3<false><<<dim3(8, 9, 10), 256, 0, stream>>>(
        B1, B2, r3_w + (size_t)i * 2 * 691200 + 691200, r3_bn + i * 1280 + 640);
    k_mean<<<1440, 256, 0, stream>>>(B2, YM);
    k_ca<<<1, 256, 0, stream>>>(YM, ca_w1 + i * 1600, ca_b1 + i * 10, ca_bn1 + i * 40,
                                ca_w2 + i * 1600, ca_b2 + i * 160, ca_bn2 + i * 640, Y2);
    k_sadd<<<23040, 256, 0, stream>>>(B0, B2, Y2);
  }
  k_conv3<true><<<dim3(8, 9, 10), 256, 0, stream>>>(B0, B1, c3_w, c3_bn);
  k_c4<<<144, 256, 0, stream>>>(B1, c4_w, SC);
  k_out<<<16, 256, 0, stream>>>(SC, (float*)d_out);
}

// Round 3
// 3525.618 us; speedup vs baseline: 2.3980x; 2.3980x over previous
//
#include <hip/hip_runtime.h>
#include <hip/hip_bf16.h>
#include <math.h>

// ---------------- constants ----------------
constexpr int SLICE = 81 * 4096;   // per-channel (a,y,x) slab for 81-view stage
constexpr float EPSB = 1e-5f;

// padded tower volume: [11][66][66][160] fp32, channel-last
constexpr int PZS = 4356 * 160;    // z-stride in elems (66*66*160)
constexpr int PYS = 66 * 160;      // y-stride
constexpr size_t PVOL = 11ull * 66 * 66 * 160;  // 7,666,560 elems

// workspace offsets (floats)
constexpr size_t OFF_HBUF  = 0;           // 16*SLICE
constexpr size_t OFF_T16   = 5308416;     // 16*SLICE (FEAT = first 8*SLICE)
constexpr size_t OFF_MASK  = 10616832;    // 81*4096
constexpr size_t OFF_INVM  = 10948608;    // 4096
constexpr size_t OFF_A     = 10952704;    // 648*160
constexpr size_t OFF_SC    = 11056384;    // 36864
constexpr size_t OFF_YM    = 11093248;    // 1440
constexpr size_t OFF_Y2    = 11094688;    // 1440
constexpr size_t OFF_YMP   = 11096128;    // 288*160 = 46080
constexpr size_t OFF_PA    = 11142208;    // PVOL
constexpr size_t OFF_PB    = 18808768;    // PVOL
constexpr size_t OFF_PC    = 26475328;    // PVOL -> end 34141888 floats
// ushort (bf16) weight region, element offsets from (ushort*)d_ws:
constexpr size_t UOFF_WH = 2ull * 34141888;          // 7 layers * 691200 (hi)
constexpr size_t UOFF_WL = UOFF_WH + 7ull * 691200;  // 7 layers * 691200 (lo)

typedef short s16x8 __attribute__((ext_vector_type(8)));
typedef short s16x4 __attribute__((ext_vector_type(4)));
typedef float f32x4 __attribute__((ext_vector_type(4)));

__device__ __forceinline__ float lrelu_f(float v) { return v >= 0.f ? v : 0.1f * v; }
__device__ __forceinline__ float b2f(unsigned short s) {
  union { float f; unsigned u; } z; z.u = ((unsigned)s) << 16; return z.f;
}
__device__ __forceinline__ unsigned short f2b(float f) {
  __hip_bfloat16 h = __float2bfloat16(f);
  return *(unsigned short*)&h;
}

// ---------------- stage A: unshuffle + if0 conv + bn ----------------
__global__ __launch_bounds__(256) void k_if0(const float* __restrict__ x,
                                             const float* __restrict__ w0,
                                             const float* __restrict__ bn0,
                                             float* __restrict__ hb) {
  int a = blockIdx.x;
  int p = blockIdx.y * 256 + threadIdx.x;
  int y = p >> 6, xx = p & 63;
  int ai = a / 9, aj = a % 9;
  float v[3][3];
#pragma unroll
  for (int dy = 0; dy < 3; ++dy) {
    int gy = y + dy - 1;
#pragma unroll
    for (int dx = 0; dx < 3; ++dx) {
      int gx = xx + dx - 1;
      v[dy][dx] = (gy >= 0 && gy < 64 && gx >= 0 && gx < 64)
                      ? x[(ai * 64 + gy) * 576 + aj * 64 + gx] : 0.f;
    }
  }
#pragma unroll
  for (int c = 0; c < 16; ++c) {
    float acc = 0.f;
#pragma unroll
    for (int t = 0; t < 9; ++t) acc += w0[c * 9 + t] * v[t / 3][t % 3];
    float g = bn0[c], b = bn0[16 + c], m = bn0[32 + c], vv = bn0[48 + c];
    hb[(size_t)c * SLICE + a * 4096 + p] = (acc - m) * (g * rsqrtf(vv + EPSB)) + b;
  }
}

// ---------------- stage B: per-slice 3x3 conv ----------------
template <int CI, int CO, bool BIAS, bool BN, bool LRELU, bool RESADD>
__global__ __launch_bounds__(256) void k_cslice(const float* __restrict__ in,
                                                float* __restrict__ out,
                                                const float* __restrict__ w,
                                                const float* __restrict__ bias,
                                                const float* __restrict__ bnp) {
  __shared__ __align__(16) float in_t[CI][18][18];
  __shared__ __align__(16) float w_l[CI * 9 * CO];
  int a = blockIdx.x;
  int tile = blockIdx.y;
  int y0 = (tile >> 2) * 16, x0 = (tile & 3) * 16;
  int tid = threadIdx.x;
  for (int idx = tid; idx < CI * 324; idx += 256) {
    int ci = idx / 324, r = idx % 324;
    int yy = r / 18, xx = r % 18;
    int gy = y0 + yy - 1, gx = x0 + xx - 1;
    in_t[ci][yy][xx] = (gy >= 0 && gy < 64 && gx >= 0 && gx < 64)
                           ? in[(size_t)ci * SLICE + a * 4096 + gy * 64 + gx] : 0.f;
  }
  for (int idx = tid; idx < CI * 9 * CO; idx += 256) {
    int co = idx % CO;
    int rest = idx / CO;
    int ci = rest / 9, t = rest % 9;
    w_l[idx] = w[((size_t)co * CI + ci) * 9 + t];
  }
  __syncthreads();
  int ty = tid >> 4, tx = tid & 15;
  float acc[CO];
#pragma unroll
  for (int co = 0; co < CO; ++co) acc[co] = 0.f;
  for (int ci = 0; ci < CI; ++ci) {
#pragma unroll
    for (int t = 0; t < 9; ++t) {
      float v = in_t[ci][ty + t / 3][tx + t % 3];
      const float4* wr = (const float4*)&w_l[(ci * 9 + t) * CO];
#pragma unroll
      for (int q = 0; q < CO / 4; ++q) {
        float4 w4 = wr[q];
        acc[q * 4 + 0] += w4.x * v;
        acc[q * 4 + 1] += w4.y * v;
        acc[q * 4 + 2] += w4.z * v;
        acc[q * 4 + 3] += w4.w * v;
      }
    }
  }
  size_t po = (size_t)a * 4096 + (y0 + ty) * 64 + (x0 + tx);
#pragma unroll
  for (int co = 0; co < CO; ++co) {
    float val = acc[co];
    if (BIAS) val += bias[co];
    if (BN) {
      float g = bnp[co], b = bnp[CO + co], m = bnp[2 * CO + co], vv = bnp[3 * CO + co];
      val = (val - m) * (g * rsqrtf(vv + EPSB)) + b;
    }
    if (LRELU) val = lrelu_f(val);
    if (RESADD) out[(size_t)co * SLICE + po] += val;
    else        out[(size_t)co * SLICE + po] = val;
  }
}

// ---------------- mask generation ----------------
__device__ __forceinline__ float img_at(const float* __restrict__ x, int i, int j, int yy, int xx) {
  if (yy < 0 || yy >= 64 || xx < 0 || xx >= 64) return 0.f;
  return x[(i * 64 + yy) * 576 + j * 64 + xx];
}

__global__ __launch_bounds__(256) void k_mask(const float* __restrict__ x,
                                              const float* __restrict__ disp,
                                              float* __restrict__ mask,
                                              float* __restrict__ invm) {
  int p = blockIdx.x * 256 + threadIdx.x;
  int y = p >> 6, xx = p & 63;
  float d = -disp[p];
  float ref = x[(4 * 64 + y) * 576 + 4 * 64 + xx];
  float ssum = 0.f;
  float xbase = (float)xx * (64.0f / 63.0f);
  float ybase = (float)y * (64.0f / 63.0f);
  for (int i = 0; i < 9; ++i) {
    float py = ybase + (float)(i - 4) * d - 0.5f;
    float y0f = floorf(py);
    float fy = py - y0f;
    int y0 = (int)y0f;
    for (int j = 0; j < 9; ++j) {
      float px = xbase + (float)(j - 4) * d - 0.5f;
      float x0f = floorf(px);
      float fx = px - x0f;
      int x0 = (int)x0f;
      float val = img_at(x, i, j, y0, x0) * (1.f - fx) * (1.f - fy)
                + img_at(x, i, j, y0, x0 + 1) * fx * (1.f - fy)
                + img_at(x, i, j, y0 + 1, x0) * (1.f - fx) * fy
                + img_at(x, i, j, y0 + 1, x0 + 1) * fx * fy;
      float diff = (i == 4 && j == 4) ? 0.f : fabsf(val - ref);
      float m = 1.f - diff;
      m = m * m;
      mask[(i * 9 + j) * 4096 + p] = m;
      ssum += m;
    }
  }
  invm[p] = 81.f / ssum;
}

// ---------------- A = sq_w (.) fuse_w ----------------
__global__ __launch_bounds__(256) void k_A(const float* __restrict__ sq_w,
                                           const float* __restrict__ fuse_w,
                                           float* __restrict__ A) {
  int guv = blockIdx.x;
  int g = guv / 81, uv = guv % 81;
  int o = threadIdx.x;
  if (o >= 160) return;
  float acc = 0.f;
  for (int o2 = 0; o2 < 64; ++o2)
    acc += sq_w[(size_t)o * 512 + g * 64 + o2] * fuse_w[(size_t)(g * 64 + o2) * 81 + uv];
  A[(size_t)guv * 160 + o] = acc;
}

// ---------------- fused cost volume + squeeze -> fp32 padded ----------------
__global__ __launch_bounds__(256) void k_costsq(const float* __restrict__ feat,
                                                const float* __restrict__ mask,
                                                const float* __restrict__ invm,
                                                const float* __restrict__ A,
                                                const float* __restrict__ sq_bn,
                                                float* __restrict__ out) {
  __shared__ float s[8 * 81 * 16];
  int xt = blockIdx.x;
  int y  = blockIdx.y;
  int dI = blockIdx.z;
  int dd = dI - 4;
  int x0 = xt * 16;
  int tid = threadIdx.x;
  for (int idx = tid; idx < 8 * 81 * 16; idx += 256) {
    int g = idx / (81 * 16);
    int r = idx % (81 * 16);
    int uv = r / 16;
    int xl = r & 15;
    int u = uv / 9, v = uv % 9;
    int ys = y + (4 - u) * dd;
    int xs = x0 + xl + (4 - v) * dd;
    float f = (ys >= 0 && ys < 64 && xs >= 0 && xs < 64)
                  ? feat[(size_t)g * SLICE + uv * 4096 + ys * 64 + xs] : 0.f;
    s[idx] = f * mask[uv * 4096 + y * 64 + x0 + xl];
  }
  __syncthreads();
  int xl = tid & 15, ob = tid >> 4;
  float acc[10];
#pragma unroll
  for (int k = 0; k < 10; ++k) acc[k] = 0.f;
  for (int g = 0; g < 8; ++g) {
    for (int uv = 0; uv < 81; ++uv) {
      float sv = s[(g * 81 + uv) * 16 + xl];
      const float* Ar = &A[(size_t)(g * 81 + uv) * 160];
#pragma unroll
      for (int k = 0; k < 10; ++k) acc[k] += Ar[ob + 16 * k] * sv;
    }
  }
  float im = invm[y * 64 + x0 + xl];
  size_t base = (size_t)(dI + 1) * PZS + (size_t)(y + 1) * PYS + (size_t)(x0 + xl + 1) * 160;
#pragma unroll
  for (int k = 0; k < 10; ++k) {
    int o = ob + 16 * k;
    float val = acc[k] * im;
    float g = sq_bn[o], b = sq_bn[160 + o], m = sq_bn[320 + o], vv = sq_bn[480 + o];
    val = (val - m) * (g * rsqrtf(vv + EPSB)) + b;
    out[base + o] = lrelu_f(val);
  }
}

// ---------------- weight transform: fp32 [co][ci][27] -> bf16 hi/lo [t][co][ci] ----------------
__global__ __launch_bounds__(256) void k_wt(const float* __restrict__ w,
                                            unsigned short* __restrict__ oh,
                                            unsigned short* __restrict__ ol) {
  int i = blockIdx.x * 256 + threadIdx.x;
  if (i >= 691200) return;
  int t = i / 25600, r = i % 25600;   // r = co*160+ci
  float x = w[(size_t)r * 27 + t];
  unsigned short h = f2b(x);
  oh[i] = h;
  ol[i] = f2b(x - b2f(h));
}

// ---------------- MFMA split-precision implicit-GEMM 3x3x3 conv, 160->160 ----------------
// fp32 in/out; on-the-fly hi/lo bf16 split; 3 MFMA passes (hi*hi + hi*lo + lo*hi).
template <bool LRELU>
__global__ __launch_bounds__(256) void k_mconv(const float* __restrict__ in,
                                               float* __restrict__ out,
                                               const unsigned short* __restrict__ wh,
                                               const unsigned short* __restrict__ wl,
                                               const float* __restrict__ bnp) {
  __shared__ short Ah[66 * 168];   // hi plane, row stride 168
  __shared__ short Al[66 * 168];   // lo plane
  int zy = blockIdx.x;             // 0..575
  int z = zy / 64, y = zy % 64;
  int tid = threadIdx.x;
  int lane = tid & 63;
  int wave = tid >> 6;
  int wm = wave >> 1, wn = wave & 1;   // 2x2 wave grid, wave tile 32(M)x80(N)
  int lr = lane & 15;
  int lq = lane >> 4;

  f32x4 acc[2][5];
#pragma unroll
  for (int i = 0; i < 2; ++i)
#pragma unroll
    for (int j = 0; j < 5; ++j) acc[i][j] = (f32x4){0.f, 0.f, 0.f, 0.f};

  for (int dzy = 0; dzy < 9; ++dzy) {
    int dz = dzy / 3, dy = dzy % 3;
    const float* src = in + (size_t)(z + dz) * PZS + (size_t)(y + dy) * PYS;
    __syncthreads();
    for (int v = tid; v < 2640; v += 256) {
      float4 f = *(const float4*)&src[v * 4];
      int row = v / 40, col = (v % 40) * 4;
      s16x4 hv, lv;
      {
        unsigned short h0 = f2b(f.x); hv[0] = h0; lv[0] = f2b(f.x - b2f(h0));
        unsigned short h1 = f2b(f.y); hv[1] = h1; lv[1] = f2b(f.y - b2f(h1));
        unsigned short h2 = f2b(f.z); hv[2] = h2; lv[2] = f2b(f.z - b2f(h2));
        unsigned short h3 = f2b(f.w); hv[3] = h3; lv[3] = f2b(f.w - b2f(h3));
      }
      *(s16x4*)&Ah[row * 168 + col] = hv;
      *(s16x4*)&Al[row * 168 + col] = lv;
    }
    __syncthreads();
#pragma unroll 1
    for (int dx = 0; dx < 3; ++dx) {
      const unsigned short* wht = wh + (size_t)(dzy * 3 + dx) * 25600;
      const unsigned short* wlt = wl + (size_t)(dzy * 3 + dx) * 25600;
#pragma unroll
      for (int ks = 0; ks < 5; ++ks) {
        int r0 = (wm * 32 + lr + dx) * 168 + ks * 32 + lq * 8;
        int r1 = (wm * 32 + 16 + lr + dx) * 168 + ks * 32 + lq * 8;
        s16x8 a0h = *(const s16x8*)&Ah[r0];
        s16x8 a1h = *(const s16x8*)&Ah[r1];
        s16x8 a0l = *(const s16x8*)&Al[r0];
        s16x8 a1l = *(const s16x8*)&Al[r1];
#pragma unroll
        for (int nf = 0; nf < 5; ++nf) {
          size_t wo = (size_t)(wn * 80 + nf * 16 + lr) * 160 + ks * 32 + lq * 8;
          s16x8 bh = *(const s16x8*)&wht[wo];
          s16x8 bl = *(const s16x8*)&wlt[wo];
          acc[0][nf] = __builtin_amdgcn_mfma_f32_16x16x32_bf16(a0h, bh, acc[0][nf], 0, 0, 0);
          acc[0][nf] = __builtin_amdgcn_mfma_f32_16x16x32_bf16(a0h, bl, acc[0][nf], 0, 0, 0);
          acc[0][nf] = __builtin_amdgcn_mfma_f32_16x16x32_bf16(a0l, bh, acc[0][nf], 0, 0, 0);
          acc[1][nf] = __builtin_amdgcn_mfma_f32_16x16x32_bf16(a1h, bh, acc[1][nf], 0, 0, 0);
          acc[1][nf] = __builtin_amdgcn_mfma_f32_16x16x32_bf16(a1h, bl, acc[1][nf], 0, 0, 0);
          acc[1][nf] = __builtin_amdgcn_mfma_f32_16x16x32_bf16(a1l, bh, acc[1][nf], 0, 0, 0);
        }
      }
    }
  }
  // epilogue: BN (+lrelu), write fp32 padded
#pragma unroll
  for (int nf = 0; nf < 5; ++nf) {
    int n = wn * 80 + nf * 16 + lr;
    float sc = bnp[n] * rsqrtf(bnp[480 + n] + EPSB);
    float sh = bnp[160 + n] - bnp[320 + n] * sc;
#pragma unroll
    for (int mf = 0; mf < 2; ++mf) {
#pragma unroll
      for (int r = 0; r < 4; ++r) {
        int m = wm * 32 + mf * 16 + lq * 4 + r;
        float val = acc[mf][nf][r] * sc + sh;
        if (LRELU) val = lrelu_f(val);
        out[(size_t)(z + 1) * PZS + (size_t)(y + 1) * PYS + (size_t)(m + 1) * 160 + n] = val;
      }
    }
  }
}

// ---------------- c4: 160 -> 1 conv (fp32) ----------------
__global__ __launch_bounds__(256) void k_c4(const float* __restrict__ in,
                                            const float* __restrict__ w,
                                            float* __restrict__ score) {
  __shared__ float L[66 * 169];
  __shared__ float red[256];
  int zy = blockIdx.x;
  int z = zy / 64, y = zy % 64;
  int tid = threadIdx.x;
  int x = tid & 63, q = tid >> 6;  // q: ci-quarter 0..3
  float acc = 0.f;
  for (int dzy = 0; dzy < 9; ++dzy) {
    int dz = dzy / 3, dy = dzy % 3;
    const float* src = in + (size_t)(z + dz) * PZS + (size_t)(y + dy) * PYS;
    __syncthreads();
    for (int v = tid; v < 10560; v += 256) {
      int row = v / 160, col = v % 160;
      L[row * 169 + col] = src[v];
    }
    __syncthreads();
#pragma unroll 1
    for (int dx = 0; dx < 3; ++dx) {
      int t = dzy * 3 + dx;
      for (int ci = q * 40; ci < q * 40 + 40; ++ci)
        acc += L[(x + dx) * 169 + ci] * w[ci * 27 + t];
    }
  }
  red[tid] = acc;
  __syncthreads();
  if (q == 0)
    score[z * 4096 + y * 64 + x] = red[x] + red[64 + x] + red[128 + x] + red[192 + x];
}

// ---------------- channel attention ----------------
__global__ __launch_bounds__(256) void k_mean1(const float* __restrict__ in,
                                               float* __restrict__ ymp) {
  int z = blockIdx.x, yg = blockIdx.y, xq = blockIdx.z;
  int c = threadIdx.x;
  if (c >= 160) return;
  float s = 0.f;
  for (int yy = 0; yy < 8; ++yy) {
    int y = yg * 8 + yy;
    for (int xl = 0; xl < 16; ++xl) {
      int x = xq * 16 + xl;
      s += in[(size_t)(z + 1) * PZS + (size_t)(y + 1) * PYS + (size_t)(x + 1) * 160 + c];
    }
  }
  ymp[((z * 8 + yg) * 4 + xq) * 160 + c] = s;
}

__global__ __launch_bounds__(256) void k_mean2(const float* __restrict__ ymp,
                                               float* __restrict__ ym) {
  int idx = blockIdx.x * 256 + threadIdx.x;  // c*9+z
  if (idx >= 1440) return;
  int c = idx / 9, z = idx % 9;
  float s = 0.f;
  for (int p = 0; p < 32; ++p) s += ymp[(z * 32 + p) * 160 + c];
  ym[idx] = s * (1.f / 4096.f);
}

__global__ __launch_bounds__(256) void k_ca(const float* __restrict__ ym,
                                            const float* __restrict__ w1,
                                            const float* __restrict__ b1,
                                            const float* __restrict__ bn1,
                                            const float* __restrict__ w2,
                                            const float* __restrict__ b2,
                                            const float* __restrict__ bn2,
                                            float* __restrict__ y2) {
  __shared__ float yml[1440];
  __shared__ float yy[90];
  for (int i = threadIdx.x; i < 1440; i += 256) yml[i] = ym[i];
  __syncthreads();
  if (threadIdx.x < 90) {
    int c = threadIdx.x / 9, z = threadIdx.x % 9;
    float acc = b1[c];
    for (int ci = 0; ci < 160; ++ci) acc += w1[c * 160 + ci] * yml[ci * 9 + z];
    float g = bn1[c], b = bn1[10 + c], m = bn1[20 + c], vv = bn1[30 + c];
    acc = (acc - m) * (g * rsqrtf(vv + EPSB)) + b;
    yy[threadIdx.x] = lrelu_f(acc);
  }
  __syncthreads();
  for (int i = threadIdx.x; i < 1440; i += 256) {
    int c = i / 9, z = i % 9;
    float acc = b2[c];
#pragma unroll
    for (int k = 0; k < 10; ++k) acc += w2[c * 10 + k] * yy[k * 9 + z];
    float g = bn2[c], b = bn2[160 + c], m = bn2[320 + c], vv = bn2[480 + c];
    acc = (acc - m) * (g * rsqrtf(vv + EPSB)) + b;
    y2[i] = 1.f / (1.f + expf(-acc));
  }
}

__global__ __launch_bounds__(256) void k_sadd(float* __restrict__ buf,
                                              const float* __restrict__ t,
                                              const float* __restrict__ y2) {
  int i = blockIdx.x * 256 + threadIdx.x;  // < 36864*160
  int p = i / 160, c = i % 160;
  int z = p >> 12, r = p & 4095;
  int y = r >> 6, x = r & 63;
  size_t a = (size_t)(z + 1) * PZS + (size_t)(y + 1) * PYS + (size_t)(x + 1) * 160 + c;
  buf[a] += t[a] * y2[c * 9 + z];
}

// ---------------- softmax + expectation ----------------
__global__ __launch_bounds__(256) void k_out(const float* __restrict__ score,
                                             float* __restrict__ out) {
  int p = blockIdx.x * 256 + threadIdx.x;
  float v[9];
  float mx = -1e30f;
#pragma unroll
  for (int z = 0; z < 9; ++z) {
    v[z] = score[z * 4096 + p];
    mx = fmaxf(mx, v[z]);
  }
  float s = 0.f, r = 0.f;
#pragma unroll
  for (int z = 0; z < 9; ++z) {
    float e = expf(v[z] - mx);
    s += e;
    r += e * (float)(z - 4);
  }
  out[p] = r / s;
}

// ---------------- launch ----------------
extern "C" void kernel_launch(void* const* d_in, const int* in_sizes, int n_in,
                              void* d_out, int out_size, void* d_ws, size_t ws_size,
                              hipStream_t stream) {
  const float* X      = (const float*)d_in[0];
  const float* disp   = (const float*)d_in[1];
  const float* if_w0  = (const float*)d_in[2];
  const float* if_bn0 = (const float*)d_in[3];
  const float* resb_w = (const float*)d_in[4];
  const float* resb_b = (const float*)d_in[5];
  const float* resb_bn= (const float*)d_in[6];
  const float* if_w1  = (const float*)d_in[7];
  const float* if_bn1 = (const float*)d_in[8];
  const float* if_w2  = (const float*)d_in[9];
  const float* if_bn2 = (const float*)d_in[10];
  const float* last_w = (const float*)d_in[11];
  const float* fuse_w = (const float*)d_in[12];
  const float* sq_w   = (const float*)d_in[13];
  const float* sq_bn  = (const float*)d_in[14];
  const float* c1_w   = (const float*)d_in[15];
  const float* c1_bn  = (const float*)d_in[16];
  const float* c2_w   = (const float*)d_in[17];
  const float* c2_bn  = (const float*)d_in[18];
  const float* c3_w   = (const float*)d_in[19];
  const float* c3_bn  = (const float*)d_in[20];
  const float* c4_w   = (const float*)d_in[21];
  const float* r3_w   = (const float*)d_in[22];
  const float* r3_bn  = (const float*)d_in[23];
  const float* ca_w1  = (const float*)d_in[24];
  const float* ca_b1  = (const float*)d_in[25];
  const float* ca_bn1 = (const float*)d_in[26];
  const float* ca_w2  = (const float*)d_in[27];
  const float* ca_b2  = (const float*)d_in[28];
  const float* ca_bn2 = (const float*)d_in[29];

  float* ws   = (float*)d_ws;
  float* HB   = ws + OFF_HBUF;
  float* T16  = ws + OFF_T16;
  float* FEAT = T16;
  float* MASK = ws + OFF_MASK;
  float* INVM = ws + OFF_INVM;
  float* Abuf = ws + OFF_A;
  float* SC   = ws + OFF_SC;
  float* YM   = ws + OFF_YM;
  float* Y2   = ws + OFF_Y2;
  float* YMP  = ws + OFF_YMP;
  float* PA   = ws + OFF_PA;
  float* PB   = ws + OFF_PB;
  float* PC   = ws + OFF_PC;
  unsigned short* U  = (unsigned short*)d_ws;
  unsigned short* WH = U + UOFF_WH;
  unsigned short* WL = U + UOFF_WL;

  // zero padded volumes (borders must be 0; ws is poisoned before timing)
  hipMemsetAsync(PA, 0, PVOL * 4, stream);
  hipMemsetAsync(PB, 0, PVOL * 4, stream);
  hipMemsetAsync(PC, 0, PVOL * 4, stream);

  // weight hi/lo transforms for the 7 tower layers
  const float* LW[7] = {c1_w, c2_w, r3_w, r3_w + 691200, r3_w + 2 * 691200,
                        r3_w + 3 * 691200, c3_w};
  for (int l = 0; l < 7; ++l)
    k_wt<<<2700, 256, 0, stream>>>(LW[l], WH + (size_t)l * 691200,
                                   WL + (size_t)l * 691200);

  // stage A + slice stack (fp32)
  k_if0<<<dim3(81, 16), 256, 0, stream>>>(X, if_w0, if_bn0, HB);
  for (int i = 0; i < 8; ++i) {
    k_cslice<16, 16, true, true, true, false><<<dim3(81, 16), 256, 0, stream>>>(
        HB, T16, resb_w + i * 4608, resb_b + i * 32, resb_bn + i * 128);
    k_cslice<16, 16, true, true, false, true><<<dim3(81, 16), 256, 0, stream>>>(
        T16, HB, resb_w + i * 4608 + 2304, resb_b + i * 32 + 16, resb_bn + i * 128 + 64);
  }
  k_cslice<16, 16, false, true, true, false><<<dim3(81, 16), 256, 0, stream>>>(
      HB, T16, if_w1, nullptr, if_bn1);
  k_cslice<16, 8, false, true, true, false><<<dim3(81, 16), 256, 0, stream>>>(
      T16, HB, if_w2, nullptr, if_bn2);
  k_cslice<8, 8, false, false, false, false><<<dim3(81, 16), 256, 0, stream>>>(
      HB, FEAT, last_w, nullptr, nullptr);

  // mask + A + fused cost/squeeze -> PA (fp32 padded)
  k_mask<<<16, 256, 0, stream>>>(X, disp, MASK, INVM);
  k_A<<<648, 256, 0, stream>>>(sq_w, fuse_w, Abuf);
  k_costsq<<<dim3(4, 64, 9), 256, 0, stream>>>(FEAT, MASK, INVM, Abuf, sq_bn, PA);

  // tower (split-precision MFMA)
  k_mconv<true><<<576, 256, 0, stream>>>(PA, PB, WH + 0ull * 691200, WL + 0ull * 691200, c1_bn);
  k_mconv<true><<<576, 256, 0, stream>>>(PB, PA, WH + 1ull * 691200, WL + 1ull * 691200, c2_bn);
  for (int i = 0; i < 2; ++i) {
    k_mconv<true><<<576, 256, 0, stream>>>(PA, PB, WH + (size_t)(2 + 2 * i) * 691200,
                                           WL + (size_t)(2 + 2 * i) * 691200, r3_bn + i * 1280);
    k_mconv<false><<<576, 256, 0, stream>>>(PB, PC, WH + (size_t)(3 + 2 * i) * 691200,
                                            WL + (size_t)(3 + 2 * i) * 691200,
                                            r3_bn + i * 1280 + 640);
    k_mean1<<<dim3(9, 8, 4), 256, 0, stream>>>(PC, YMP);
    k_mean2<<<6, 256, 0, stream>>>(YMP, YM);
    k_ca<<<1, 256, 0, stream>>>(YM, ca_w1 + i * 1600, ca_b1 + i * 10, ca_bn1 + i * 40,
                                ca_w2 + i * 1600, ca_b2 + i * 160, ca_bn2 + i * 640, Y2);
    k_sadd<<<23040, 256, 0, stream>>>(PA, PC, Y2);
  }
  k_mconv<true><<<576, 256, 0, stream>>>(PA, PB, WH + 6ull * 691200, WL + 6ull * 691200, c3_bn);
  k_c4<<<576, 256, 0, stream>>>(PB, c4_w, SC);
  k_out<<<16, 256, 0, stream>>>(SC, (float*)d_out);
}

// Round 4
// 2545.694 us; speedup vs baseline: 3.3210x; 1.3849x over previous
//
#include <hip/hip_runtime.h>
#include <hip/hip_bf16.h>
#include <math.h>

// ---------------- constants ----------------
constexpr float EPSB = 1e-5f;

// slice stage: channel-last padded [81][66][66][16] fp32
constexpr int SAS = 69696;         // slab stride (66*66*16)
constexpr int SRS = 1056;          // row stride (66*16)
constexpr size_t SVOL = 81ull * SAS;   // 5,645,376

// tower volume: [11][66][66][160] fp32 channel-last
constexpr int PZS = 696960;        // 4356*160
constexpr int PYS = 10560;         // 66*160
constexpr size_t PVOL = 11ull * 4356 * 160;  // 7,666,560

// workspace offsets (floats)
constexpr size_t OFF_SA   = 0;           // SVOL
constexpr size_t OFF_SB   = 5645376;     // SVOL
// PC (tower scratch) overlays SA/SB (dead by then): OFF_PC = 0
constexpr size_t OFF_MASK = 11290752;    // 81*4096
constexpr size_t OFF_INVM = 11622528;    // 4096
constexpr size_t OFF_SC   = 11626624;    // 36864
constexpr size_t OFF_YM   = 11663488;    // 1440
constexpr size_t OFF_Y2   = 11664928;    // 1440
constexpr size_t OFF_YMP  = 11666368;    // 46080
constexpr size_t OFF_PA   = 11712448;    // PVOL
constexpr size_t OFF_PB   = 19379008;    // PVOL -> end 27,045,568 floats
// ushort regions (element offsets from (ushort*)d_ws)
constexpr size_t UOFF_WH  = 54091136;            // 7*691200 tower hi
constexpr size_t UOFF_WL  = 58929536;            // 7*691200 tower lo
constexpr size_t UOFF_WSH = 63767936;            // 19*2560 slice hi
constexpr size_t UOFF_WSL = 63816576;            // 19*2560 slice lo
constexpr size_t UOFF_ABH = 63865216;            // 160*672 cost-B hi
constexpr size_t UOFF_ABL = 63972736;            // 160*672 cost-B lo

typedef short s16x8 __attribute__((ext_vector_type(8)));
typedef short s16x4 __attribute__((ext_vector_type(4)));
typedef float f32x4 __attribute__((ext_vector_type(4)));

__device__ __forceinline__ float lrelu_f(float v) { return v >= 0.f ? v : 0.1f * v; }
__device__ __forceinline__ float b2f(unsigned short s) {
  union { float f; unsigned u; } z; z.u = ((unsigned)s) << 16; return z.f;
}
__device__ __forceinline__ unsigned short f2b(float f) {
  __hip_bfloat16 h = __float2bfloat16(f);
  return *(unsigned short*)&h;
}

// ---------------- stage A: unshuffle + if0 conv + bn -> channel-last SA ----------------
__global__ __launch_bounds__(256) void k_if0(const float* __restrict__ x,
                                             const float* __restrict__ w0,
                                             const float* __restrict__ bn0,
                                             float* __restrict__ SA) {
  int a = blockIdx.x;
  int p = blockIdx.y * 256 + threadIdx.x;
  int y = p >> 6, xx = p & 63;
  int ai = a / 9, aj = a % 9;
  float v[3][3];
#pragma unroll
  for (int dy = 0; dy < 3; ++dy) {
    int gy = y + dy - 1;
#pragma unroll
    for (int dx = 0; dx < 3; ++dx) {
      int gx = xx + dx - 1;
      v[dy][dx] = (gy >= 0 && gy < 64 && gx >= 0 && gx < 64)
                      ? x[(ai * 64 + gy) * 576 + aj * 64 + gx] : 0.f;
    }
  }
  float o16[16];
#pragma unroll
  for (int c = 0; c < 16; ++c) {
    float acc = 0.f;
#pragma unroll
    for (int t = 0; t < 9; ++t) acc += w0[c * 9 + t] * v[t / 3][t % 3];
    float g = bn0[c], b = bn0[16 + c], m = bn0[32 + c], vv = bn0[48 + c];
    o16[c] = (acc - m) * (g * rsqrtf(vv + EPSB)) + b;
  }
  float* dst = SA + (size_t)a * SAS + (size_t)(y + 1) * SRS + (size_t)(xx + 1) * 16;
#pragma unroll
  for (int q = 0; q < 4; ++q)
    *(float4*)&dst[q * 4] = make_float4(o16[q*4], o16[q*4+1], o16[q*4+2], o16[q*4+3]);
}

// ---------------- slice weight transform: -> bf16 hi/lo [conv][co(16)][k=t*16+ci (160)] ----------------
__global__ __launch_bounds__(256) void k_wslice(const float* __restrict__ resb_w,
                                                const float* __restrict__ if1_w,
                                                const float* __restrict__ if2_w,
                                                const float* __restrict__ last_w,
                                                unsigned short* __restrict__ WSH,
                                                unsigned short* __restrict__ WSL) {
  int c = blockIdx.x;  // 0..18
  for (int idx = threadIdx.x; idx < 2560; idx += 256) {
    int o = idx / 160, k = idx % 160;
    int t = k >> 4, ci = k & 15;
    float v = 0.f;
    if (t < 9) {
      if (c < 16)       v = resb_w[((size_t)c * 256 + o * 16 + ci) * 9 + t];
      else if (c == 16) v = if1_w[(size_t)(o * 16 + ci) * 9 + t];
      else if (c == 17) v = (o < 8) ? if2_w[(size_t)(o * 16 + ci) * 9 + t] : 0.f;
      else              v = (o < 8 && ci < 8) ? last_w[(size_t)(o * 8 + ci) * 9 + t] : 0.f;
    }
    unsigned short h = f2b(v);
    WSH[c * 2560 + idx] = h;
    WSL[c * 2560 + idx] = f2b(v - b2f(h));
  }
}

// ---------------- tower weight transform (coalesced): [co][ci][27] -> hi/lo [t][co*160+ci] ----------------
__global__ __launch_bounds__(256) void k_wt7(const float* __restrict__ c1,
                                             const float* __restrict__ c2,
                                             const float* __restrict__ r3,
                                             const float* __restrict__ c3,
                                             unsigned short* __restrict__ WH,
                                             unsigned short* __restrict__ WL) {
  __shared__ float L[6912];
  int l = blockIdx.y;
  const float* w = (l == 0) ? c1 : (l == 1) ? c2 : (l < 6) ? r3 + (size_t)(l - 2) * 691200 : c3;
  size_t base = (size_t)blockIdx.x * 256;
  for (int i = threadIdx.x; i < 6912; i += 256) L[i] = w[base * 27 + i];
  __syncthreads();
  unsigned short* wh = WH + (size_t)l * 691200;
  unsigned short* wl = WL + (size_t)l * 691200;
  int r = (int)base + threadIdx.x;
#pragma unroll 1
  for (int t = 0; t < 27; ++t) {
    float v = L[threadIdx.x * 27 + t];
    unsigned short h = f2b(v);
    wh[(size_t)t * 25600 + r] = h;
    wl[(size_t)t * 25600 + r] = f2b(v - b2f(h));
  }
}

// ---------------- cost-B: (sq_w . fuse_w) -> bf16 hi/lo [o][k=uv*8+g (672)] ----------------
__global__ __launch_bounds__(192) void k_A(const float* __restrict__ sq_w,
                                           const float* __restrict__ fuse_w,
                                           unsigned short* __restrict__ ABH,
                                           unsigned short* __restrict__ ABL) {
  int k = blockIdx.x;  // 0..671
  int o = threadIdx.x;
  if (o >= 160) return;
  float acc = 0.f;
  if (k < 648) {
    int uv = k >> 3, g = k & 7;
    for (int o2 = 0; o2 < 64; ++o2)
      acc += sq_w[(size_t)o * 512 + g * 64 + o2] * fuse_w[(size_t)(g * 64 + o2) * 81 + uv];
  }
  unsigned short h = f2b(acc);
  ABH[(size_t)o * 672 + k] = h;
  ABL[(size_t)o * 672 + k] = f2b(acc - b2f(h));
}

// ---------------- mask generation ----------------
__device__ __forceinline__ float img_at(const float* __restrict__ x, int i, int j, int yy, int xx) {
  if (yy < 0 || yy >= 64 || xx < 0 || xx >= 64) return 0.f;
  return x[(i * 64 + yy) * 576 + j * 64 + xx];
}

__global__ __launch_bounds__(256) void k_mask(const float* __restrict__ x,
                                              const float* __restrict__ disp,
                                              float* __restrict__ mask,
                                              float* __restrict__ invm) {
  int p = blockIdx.x * 256 + threadIdx.x;
  int y = p >> 6, xx = p & 63;
  float d = -disp[p];
  float ref = x[(4 * 64 + y) * 576 + 4 * 64 + xx];
  float ssum = 0.f;
  float xbase = (float)xx * (64.0f / 63.0f);
  float ybase = (float)y * (64.0f / 63.0f);
  for (int i = 0; i < 9; ++i) {
    float py = ybase + (float)(i - 4) * d - 0.5f;
    float y0f = floorf(py);
    float fy = py - y0f;
    int y0 = (int)y0f;
    for (int j = 0; j < 9; ++j) {
      float px = xbase + (float)(j - 4) * d - 0.5f;
      float x0f = floorf(px);
      float fx = px - x0f;
      int x0 = (int)x0f;
      float val = img_at(x, i, j, y0, x0) * (1.f - fx) * (1.f - fy)
                + img_at(x, i, j, y0, x0 + 1) * fx * (1.f - fy)
                + img_at(x, i, j, y0 + 1, x0) * (1.f - fx) * fy
                + img_at(x, i, j, y0 + 1, x0 + 1) * fx * fy;
      float diff = (i == 4 && j == 4) ? 0.f : fabsf(val - ref);
      float m = 1.f - diff;
      m = m * m;
      mask[(i * 9 + j) * 4096 + p] = m;
      ssum += m;
    }
  }
  invm[p] = 81.f / ssum;
}

// ---------------- slice 3x3 conv, MFMA split-precision implicit GEMM ----------------
// in/out: channel-last padded [81][66][66][16] fp32. K = tap*16+ci (144 pad 160).
template <bool BN, bool LRELU, bool RESADD, int CO>
__global__ __launch_bounds__(256) void k_cs(const float* __restrict__ in,
                                            float* __restrict__ out,
                                            const unsigned short* __restrict__ wsh,
                                            const unsigned short* __restrict__ wsl,
                                            const float* __restrict__ bias,
                                            const float* __restrict__ bnp) {
  __shared__ short Ah[15840];   // [10 rows][66 px][24 shorts]
  __shared__ short Al[15840];
  int a = blockIdx.x, y0 = blockIdx.y * 8;
  int tid = threadIdx.x, lane = tid & 63, w = tid >> 6;
  int lr = lane & 15, lq = lane >> 4;
  const float* src = in + (size_t)a * SAS + (size_t)y0 * SRS;
  for (int it = tid; it < 2640; it += 256) {
    int row = it / 264, rem = it % 264;
    float4 f = *(const float4*)&src[row * SRS + rem * 4];
    int px = rem >> 2, q = rem & 3;
    s16x4 hv, lv;
    { unsigned short h = f2b(f.x); hv[0] = h; lv[0] = f2b(f.x - b2f(h)); }
    { unsigned short h = f2b(f.y); hv[1] = h; lv[1] = f2b(f.y - b2f(h)); }
    { unsigned short h = f2b(f.z); hv[2] = h; lv[2] = f2b(f.z - b2f(h)); }
    { unsigned short h = f2b(f.w); hv[3] = h; lv[3] = f2b(f.w - b2f(h)); }
    int base = (row * 66 + px) * 24 + q * 4;
    *(s16x4*)&Ah[base] = hv;
    *(s16x4*)&Al[base] = lv;
  }
  __syncthreads();
  s16x8 bh[5], bl[5];
#pragma unroll
  for (int ks = 0; ks < 5; ++ks) {
    bh[ks] = *(const s16x8*)&wsh[lr * 160 + ks * 32 + lq * 8];
    bl[ks] = *(const s16x8*)&wsl[lr * 160 + ks * 32 + lq * 8];
  }
  int offk[5];
#pragma unroll
  for (int ks = 0; ks < 5; ++ks) {
    int t = ks * 2 + (lq >> 1);
    if (t > 8) t = 8;  // k>=144: weights are zero; clamp keeps LDS read in-bounds/finite
    offk[ks] = ((t / 3) * 66 + (t % 3)) * 24 + (lq & 1) * 8;
  }
  f32x4 acc[8];
#pragma unroll
  for (int i = 0; i < 8; ++i) acc[i] = (f32x4){0.f, 0.f, 0.f, 0.f};
#pragma unroll
  for (int mf = 0; mf < 8; ++mf) {
    int gm = w * 8 + mf;
    int yl = gm >> 2, xq = gm & 3;
    int am = (yl * 66 + xq * 16 + lr) * 24;
#pragma unroll
    for (int ks = 0; ks < 5; ++ks) {
      s16x8 ah = *(const s16x8*)&Ah[am + offk[ks]];
      s16x8 al = *(const s16x8*)&Al[am + offk[ks]];
      acc[mf] = __builtin_amdgcn_mfma_f32_16x16x32_bf16(ah, bh[ks], acc[mf], 0, 0, 0);
      acc[mf] = __builtin_amdgcn_mfma_f32_16x16x32_bf16(ah, bl[ks], acc[mf], 0, 0, 0);
      acc[mf] = __builtin_amdgcn_mfma_f32_16x16x32_bf16(al, bh[ks], acc[mf], 0, 0, 0);
    }
  }
  int co = lr;
  bool coval = (CO == 16) || (co < CO);
  float sc = 1.f, sh = 0.f;
  if (BN && coval) {
    float g = bnp[co], b = bnp[CO + co], m = bnp[2 * CO + co], vv = bnp[3 * CO + co];
    sc = g * rsqrtf(vv + EPSB);
    sh = b - m * sc;
    if (bias) sh += bias[co] * sc;
  }
#pragma unroll
  for (int mf = 0; mf < 8; ++mf) {
    int gm = w * 8 + mf;
    int yl = gm >> 2, xq = gm & 3;
    if (coval) {
#pragma unroll
      for (int r = 0; r < 4; ++r) {
        int x = xq * 16 + lq * 4 + r;
        float val = acc[mf][r] * sc + sh;
        if (LRELU) val = lrelu_f(val);
        size_t oo = (size_t)a * SAS + (size_t)(y0 + yl + 1) * SRS + (size_t)(x + 1) * 16 + co;
        if (RESADD) out[oo] += val;
        else        out[oo] = val;
      }
    }
  }
}

// ---------------- fused cost volume + squeeze: MFMA split-precision ----------------
// M=64 (x row), N=160, K=672 (k=uv*8+g), 7 chunks of 96. Output -> PA fp32 padded.
__global__ __launch_bounds__(256) void k_costsq(const float* __restrict__ feat,
                                                const float* __restrict__ mask,
                                                const float* __restrict__ invm,
                                                const unsigned short* __restrict__ ABH,
                                                const unsigned short* __restrict__ ABL,
                                                const float* __restrict__ sq_bn,
                                                float* __restrict__ outPA) {
  __shared__ short Ah[6144];   // [64 x][96 k]
  __shared__ short Al[6144];
  int dI = blockIdx.x, y = blockIdx.y;
  int dd = dI - 4;
  int tid = threadIdx.x, lane = tid & 63, w = tid >> 6;
  int wm = w >> 1, wn = w & 1;
  int lr = lane & 15, lq = lane >> 4;
  f32x4 acc[2][5];
#pragma unroll
  for (int i = 0; i < 2; ++i)
#pragma unroll
    for (int j = 0; j < 5; ++j) acc[i][j] = (f32x4){0.f, 0.f, 0.f, 0.f};

  for (int ch = 0; ch < 7; ++ch) {
    __syncthreads();
    for (int it = tid; it < 768; it += 256) {
      int xl = it / 12, uvL = it % 12;
      int uv = ch * 12 + uvL;
      s16x8 hv = {0, 0, 0, 0, 0, 0, 0, 0}, lv = {0, 0, 0, 0, 0, 0, 0, 0};
      if (uv < 81) {
        int u = uv / 9, v = uv % 9;
        int ys = y + (4 - u) * dd;
        int xs = xl + (4 - v) * dd;
        if (ys >= 0 && ys < 64 && xs >= 0 && xs < 64) {
          const float* fp = feat + (size_t)uv * SAS + (size_t)(ys + 1) * SRS + (size_t)(xs + 1) * 16;
          float mv = mask[uv * 4096 + y * 64 + xl];
#pragma unroll
          for (int j = 0; j < 8; ++j) {
            float f = fp[j] * mv;
            unsigned short h = f2b(f);
            hv[j] = h;
            lv[j] = f2b(f - b2f(h));
          }
        }
      }
      *(s16x8*)&Ah[xl * 96 + uvL * 8] = hv;
      *(s16x8*)&Al[xl * 96 + uvL * 8] = lv;
    }
    __syncthreads();
#pragma unroll
    for (int kb = 0; kb < 3; ++kb) {
      int ka = kb * 32 + lq * 8;
      s16x8 a0h = *(const s16x8*)&Ah[(wm * 32 + lr) * 96 + ka];
      s16x8 a0l = *(const s16x8*)&Al[(wm * 32 + lr) * 96 + ka];
      s16x8 a1h = *(const s16x8*)&Ah[(wm * 32 + 16 + lr) * 96 + ka];
      s16x8 a1l = *(const s16x8*)&Al[(wm * 32 + 16 + lr) * 96 + ka];
      int kg = ch * 96 + ka;
#pragma unroll
      for (int nf = 0; nf < 5; ++nf) {
        int n = wn * 80 + nf * 16 + lr;
        s16x8 bh = *(const s16x8*)&ABH[(size_t)n * 672 + kg];
        s16x8 bl = *(const s16x8*)&ABL[(size_t)n * 672 + kg];
        acc[0][nf] = __builtin_amdgcn_mfma_f32_16x16x32_bf16(a0h, bh, acc[0][nf], 0, 0, 0);
        acc[0][nf] = __builtin_amdgcn_mfma_f32_16x16x32_bf16(a0h, bl, acc[0][nf], 0, 0, 0);
        acc[0][nf] = __builtin_amdgcn_mfma_f32_16x16x32_bf16(a0l, bh, acc[0][nf], 0, 0, 0);
        acc[1][nf] = __builtin_amdgcn_mfma_f32_16x16x32_bf16(a1h, bh, acc[1][nf], 0, 0, 0);
        acc[1][nf] = __builtin_amdgcn_mfma_f32_16x16x32_bf16(a1h, bl, acc[1][nf], 0, 0, 0);
        acc[1][nf] = __builtin_amdgcn_mfma_f32_16x16x32_bf16(a1l, bh, acc[1][nf], 0, 0, 0);
      }
    }
  }
#pragma unroll
  for (int nf = 0; nf < 5; ++nf) {
    int n = wn * 80 + nf * 16 + lr;
    float g = sq_bn[n], b = sq_bn[160 + n], m = sq_bn[320 + n], vv = sq_bn[480 + n];
    float sc = g * rsqrtf(vv + EPSB), sh = b - m * sc;
#pragma unroll
    for (int mf = 0; mf < 2; ++mf) {
#pragma unroll
      for (int r = 0; r < 4; ++r) {
        int x = wm * 32 + mf * 16 + lq * 4 + r;
        float val = acc[mf][nf][r] * invm[y * 64 + x];
        val = val * sc + sh;
        val = lrelu_f(val);
        outPA[(size_t)(dI + 1) * PZS + (size_t)(y + 1) * PYS + (size_t)(x + 1) * 160 + n] = val;
      }
    }
  }
}

// ---------------- tower: MFMA split-precision 3x3x3 conv 160->160 ----------------
template <bool LRELU>
__global__ __launch_bounds__(256) void k_mconv(const float* __restrict__ in,
                                               float* __restrict__ out,
                                               const unsigned short* __restrict__ wh,
                                               const unsigned short* __restrict__ wl,
                                               const float* __restrict__ bnp) {
  __shared__ short Ah[66 * 168];
  __shared__ short Al[66 * 168];
  int zy = blockIdx.x;
  int z = zy / 64, y = zy % 64;
  int tid = threadIdx.x;
  int lane = tid & 63;
  int wave = tid >> 6;
  int wm = wave >> 1, wn = wave & 1;
  int lr = lane & 15;
  int lq = lane >> 4;

  f32x4 acc[2][5];
#pragma unroll
  for (int i = 0; i < 2; ++i)
#pragma unroll
    for (int j = 0; j < 5; ++j) acc[i][j] = (f32x4){0.f, 0.f, 0.f, 0.f};

  for (int dzy = 0; dzy < 9; ++dzy) {
    int dz = dzy / 3, dy = dzy % 3;
    const float* src = in + (size_t)(z + dz) * PZS + (size_t)(y + dy) * PYS;
    __syncthreads();
    for (int v = tid; v < 2640; v += 256) {
      float4 f = *(const float4*)&src[v * 4];
      int row = v / 40, col = (v % 40) * 4;
      s16x4 hv, lv;
      { unsigned short h = f2b(f.x); hv[0] = h; lv[0] = f2b(f.x - b2f(h)); }
      { unsigned short h = f2b(f.y); hv[1] = h; lv[1] = f2b(f.y - b2f(h)); }
      { unsigned short h = f2b(f.z); hv[2] = h; lv[2] = f2b(f.z - b2f(h)); }
      { unsigned short h = f2b(f.w); hv[3] = h; lv[3] = f2b(f.w - b2f(h)); }
      *(s16x4*)&Ah[row * 168 + col] = hv;
      *(s16x4*)&Al[row * 168 + col] = lv;
    }
    __syncthreads();
#pragma unroll 1
    for (int dx = 0; dx < 3; ++dx) {
      const unsigned short* wht = wh + (size_t)(dzy * 3 + dx) * 25600;
      const unsigned short* wlt = wl + (size_t)(dzy * 3 + dx) * 25600;
#pragma unroll
      for (int ks = 0; ks < 5; ++ks) {
        int r0 = (wm * 32 + lr + dx) * 168 + ks * 32 + lq * 8;
        int r1 = (wm * 32 + 16 + lr + dx) * 168 + ks * 32 + lq * 8;
        s16x8 a0h = *(const s16x8*)&Ah[r0];
        s16x8 a1h = *(const s16x8*)&Ah[r1];
        s16x8 a0l = *(const s16x8*)&Al[r0];
        s16x8 a1l = *(const s16x8*)&Al[r1];
#pragma unroll
        for (int nf = 0; nf < 5; ++nf) {
          size_t wo = (size_t)(wn * 80 + nf * 16 + lr) * 160 + ks * 32 + lq * 8;
          s16x8 bh = *(const s16x8*)&wht[wo];
          s16x8 bl = *(const s16x8*)&wlt[wo];
          acc[0][nf] = __builtin_amdgcn_mfma_f32_16x16x32_bf16(a0h, bh, acc[0][nf], 0, 0, 0);
          acc[0][nf] = __builtin_amdgcn_mfma_f32_16x16x32_bf16(a0h, bl, acc[0][nf], 0, 0, 0);
          acc[0][nf] = __builtin_amdgcn_mfma_f32_16x16x32_bf16(a0l, bh, acc[0][nf], 0, 0, 0);
          acc[1][nf] = __builtin_amdgcn_mfma_f32_16x16x32_bf16(a1h, bh, acc[1][nf], 0, 0, 0);
          acc[1][nf] = __builtin_amdgcn_mfma_f32_16x16x32_bf16(a1h, bl, acc[1][nf], 0, 0, 0);
          acc[1][nf] = __builtin_amdgcn_mfma_f32_16x16x32_bf16(a1l, bh, acc[1][nf], 0, 0, 0);
        }
      }
    }
  }
#pragma unroll
  for (int nf = 0; nf < 5; ++nf) {
    int n = wn * 80 + nf * 16 + lr;
    float sc = bnp[n] * rsqrtf(bnp[480 + n] + EPSB);
    float sh = bnp[160 + n] - bnp[320 + n] * sc;
#pragma unroll
    for (int mf = 0; mf < 2; ++mf) {
#pragma unroll
      for (int r = 0; r < 4; ++r) {
        int m = wm * 32 + mf * 16 + lq * 4 + r;
        float val = acc[mf][nf][r] * sc + sh;
        if (LRELU) val = lrelu_f(val);
        out[(size_t)(z + 1) * PZS + (size_t)(y + 1) * PYS + (size_t)(m + 1) * 160 + n] = val;
      }
    }
  }
}

// ---------------- c4: 160 -> 1 conv (fp32) ----------------
__global__ __launch_bounds__(256) void k_c4(const float* __restrict__ in,
                                            const float* __restrict__ w,
                                            float* __restrict__ score) {
  __shared__ float L[66 * 169];
  __shared__ float red[256];
  int zy = blockIdx.x;
  int z = zy / 64, y = zy % 64;
  int tid = threadIdx.x;
  int x = tid & 63, q = tid >> 6;
  float acc = 0.f;
  for (int dzy = 0; dzy < 9; ++dzy) {
    int dz = dzy / 3, dy = dzy % 3;
    const float* src = in + (size_t)(z + dz) * PZS + (size_t)(y + dy) * PYS;
    __syncthreads();
    for (int v = tid; v < 10560; v += 256) {
      int row = v / 160, col = v % 160;
      L[row * 169 + col] = src[v];
    }
    __syncthreads();
#pragma unroll 1
    for (int dx = 0; dx < 3; ++dx) {
      int t = dzy * 3 + dx;
      for (int ci = q * 40; ci < q * 40 + 40; ++ci)
        acc += L[(x + dx) * 169 + ci] * w[ci * 27 + t];
    }
  }
  red[tid] = acc;
  __syncthreads();
  if (q == 0)
    score[z * 4096 + y * 64 + x] = red[x] + red[64 + x] + red[128 + x] + red[192 + x];
}

// ---------------- channel attention ----------------
__global__ __launch_bounds__(256) void k_mean1(const float* __restrict__ in,
                                               float* __restrict__ ymp) {
  int z = blockIdx.x, yg = blockIdx.y, xq = blockIdx.z;
  int c = threadIdx.x;
  if (c >= 160) return;
  float s = 0.f;
  for (int yy = 0; yy < 8; ++yy) {
    int y = yg * 8 + yy;
    for (int xl = 0; xl < 16; ++xl) {
      int x = xq * 16 + xl;
      s += in[(size_t)(z + 1) * PZS + (size_t)(y + 1) * PYS + (size_t)(x + 1) * 160 + c];
    }
  }
  ymp[((z * 8 + yg) * 4 + xq) * 160 + c] = s;
}

__global__ __launch_bounds__(256) void k_mean2(const float* __restrict__ ymp,
                                               float* __restrict__ ym) {
  int idx = blockIdx.x * 256 + threadIdx.x;
  if (idx >= 1440) return;
  int c = idx / 9, z = idx % 9;
  float s = 0.f;
  for (int p = 0; p < 32; ++p) s += ymp[(z * 32 + p) * 160 + c];
  ym[idx] = s * (1.f / 4096.f);
}

__global__ __launch_bounds__(256) void k_ca(const float* __restrict__ ym,
                                            const float* __restrict__ w1,
                                            const float* __restrict__ b1,
                                            const float* __restrict__ bn1,
                                            const float* __restrict__ w2,
                                            const float* __restrict__ b2,
                                            const float* __restrict__ bn2,
                                            float* __restrict__ y2) {
  __shared__ float yml[1440];
  __shared__ float yy[90];
  for (int i = threadIdx.x; i < 1440; i += 256) yml[i] = ym[i];
  __syncthreads();
  if (threadIdx.x < 90) {
    int c = threadIdx.x / 9, z = threadIdx.x % 9;
    float acc = b1[c];
    for (int ci = 0; ci < 160; ++ci) acc += w1[c * 160 + ci] * yml[ci * 9 + z];
    float g = bn1[c], b = bn1[10 + c], m = bn1[20 + c], vv = bn1[30 + c];
    acc = (acc - m) * (g * rsqrtf(vv + EPSB)) + b;
    yy[threadIdx.x] = lrelu_f(acc);
  }
  __syncthreads();
  for (int i = threadIdx.x; i < 1440; i += 256) {
    int c = i / 9, z = i % 9;
    float acc = b2[c];
#pragma unroll
    for (int k = 0; k < 10; ++k) acc += w2[c * 10 + k] * yy[k * 9 + z];
    float g = bn2[c], b = bn2[160 + c], m = bn2[320 + c], vv = bn2[480 + c];
    acc = (acc - m) * (g * rsqrtf(vv + EPSB)) + b;
    y2[i] = 1.f / (1.f + expf(-acc));
  }
}

__global__ __launch_bounds__(256) void k_sadd(float* __restrict__ buf,
                                              const float* __restrict__ t,
                                              const float* __restrict__ y2) {
  int i = blockIdx.x * 256 + threadIdx.x;
  int p = i / 160, c = i % 160;
  int z = p >> 12, r = p & 4095;
  int y = r >> 6, x = r & 63;
  size_t a = (size_t)(z + 1) * PZS + (size_t)(y + 1) * PYS + (size_t)(x + 1) * 160 + c;
  buf[a] += t[a] * y2[c * 9 + z];
}

// ---------------- softmax + expectation ----------------
__global__ __launch_bounds__(256) void k_out(const float* __restrict__ score,
                                             float* __restrict__ out) {
  int p = blockIdx.x * 256 + threadIdx.x;
  float v[9];
  float mx = -1e30f;
#pragma unroll
  for (int z = 0; z < 9; ++z) {
    v[z] = score[z * 4096 + p];
    mx = fmaxf(mx, v[z]);
  }
  float s = 0.f, r = 0.f;
#pragma unroll
  for (int z = 0; z < 9; ++z) {
    float e = expf(v[z] - mx);
    s += e;
    r += e * (float)(z - 4);
  }
  out[p] = r / s;
}

// ---------------- launch ----------------
extern "C" void kernel_launch(void* const* d_in, const int* in_sizes, int n_in,
                              void* d_out, int out_size, void* d_ws, size_t ws_size,
                              hipStream_t stream) {
  const float* X      = (const float*)d_in[0];
  const float* disp   = (const float*)d_in[1];
  const float* if_w0  = (const float*)d_in[2];
  const float* if_bn0 = (const float*)d_in[3];
  const float* resb_w = (const float*)d_in[4];
  const float* resb_b = (const float*)d_in[5];
  const float* resb_bn= (const float*)d_in[6];
  const float* if_w1  = (const float*)d_in[7];
  const float* if_bn1 = (const float*)d_in[8];
  const float* if_w2  = (const float*)d_in[9];
  const float* if_bn2 = (const float*)d_in[10];
  const float* last_w = (const float*)d_in[11];
  const float* fuse_w = (const float*)d_in[12];
  const float* sq_w   = (const float*)d_in[13];
  const float* sq_bn  = (const float*)d_in[14];
  const float* c1_w   = (const float*)d_in[15];
  const float* c1_bn  = (const float*)d_in[16];
  const float* c2_w   = (const float*)d_in[17];
  const float* c2_bn  = (const float*)d_in[18];
  const float* c3_w   = (const float*)d_in[19];
  const float* c3_bn  = (const float*)d_in[20];
  const float* c4_w   = (const float*)d_in[21];
  const float* r3_w   = (const float*)d_in[22];
  const float* r3_bn  = (const float*)d_in[23];
  const float* ca_w1  = (const float*)d_in[24];
  const float* ca_b1  = (const float*)d_in[25];
  const float* ca_bn1 = (const float*)d_in[26];
  const float* ca_w2  = (const float*)d_in[27];
  const float* ca_b2  = (const float*)d_in[28];
  const float* ca_bn2 = (const float*)d_in[29];

  float* ws   = (float*)d_ws;
  float* SA   = ws + OFF_SA;
  float* SB   = ws + OFF_SB;
  float* PC   = ws;               // overlays SA/SB (dead after costsq)
  float* MASK = ws + OFF_MASK;
  float* INVM = ws + OFF_INVM;
  float* SC   = ws + OFF_SC;
  float* YM   = ws + OFF_YM;
  float* Y2   = ws + OFF_Y2;
  float* YMP  = ws + OFF_YMP;
  float* PA   = ws + OFF_PA;
  float* PB   = ws + OFF_PB;
  unsigned short* U   = (unsigned short*)d_ws;
  unsigned short* WH  = U + UOFF_WH;
  unsigned short* WL  = U + UOFF_WL;
  unsigned short* WSH = U + UOFF_WSH;
  unsigned short* WSL = U + UOFF_WSL;
  unsigned short* ABH = U + UOFF_ABH;
  unsigned short* ABL = U + UOFF_ABL;

  hipMemsetAsync(SA, 0, SVOL * 4, stream);
  hipMemsetAsync(SB, 0, SVOL * 4, stream);
  hipMemsetAsync(PA, 0, PVOL * 4, stream);
  hipMemsetAsync(PB, 0, PVOL * 4, stream);

  k_wt7<<<dim3(100, 7), 256, 0, stream>>>(c1_w, c2_w, r3_w, c3_w, WH, WL);
  k_wslice<<<19, 256, 0, stream>>>(resb_w, if_w1, if_w2, last_w, WSH, WSL);
  k_A<<<672, 192, 0, stream>>>(sq_w, fuse_w, ABH, ABL);
  k_mask<<<16, 256, 0, stream>>>(X, disp, MASK, INVM);

  k_if0<<<dim3(81, 16), 256, 0, stream>>>(X, if_w0, if_bn0, SA);
  for (int i = 0; i < 8; ++i) {
    k_cs<true, true, false, 16><<<dim3(81, 8), 256, 0, stream>>>(
        SA, SB, WSH + (size_t)(2 * i) * 2560, WSL + (size_t)(2 * i) * 2560,
        resb_b + i * 32, resb_bn + i * 128);
    k_cs<true, false, true, 16><<<dim3(81, 8), 256, 0, stream>>>(
        SB, SA, WSH + (size_t)(2 * i + 1) * 2560, WSL + (size_t)(2 * i + 1) * 2560,
        resb_b + i * 32 + 16, resb_bn + i * 128 + 64);
  }
  k_cs<true, true, false, 16><<<dim3(81, 8), 256, 0, stream>>>(
      SA, SB, WSH + 16 * 2560, WSL + 16 * 2560, nullptr, if_bn1);
  k_cs<true, true, false, 8><<<dim3(81, 8), 256, 0, stream>>>(
      SB, SA, WSH + 17 * 2560, WSL + 17 * 2560, nullptr, if_bn2);
  k_cs<false, false, false, 8><<<dim3(81, 8), 256, 0, stream>>>(
      SA, SB, WSH + 18 * 2560, WSL + 18 * 2560, nullptr, nullptr);

  k_costsq<<<dim3(9, 64), 256, 0, stream>>>(SB, MASK, INVM, ABH, ABL, sq_bn, PA);
  hipMemsetAsync(PC, 0, PVOL * 4, stream);  // SA/SB dead; PC borders must be zero

  k_mconv<true><<<576, 256, 0, stream>>>(PA, PB, WH + 0ull * 691200, WL + 0ull * 691200, c1_bn);
  k_mconv<true><<<576, 256, 0, stream>>>(PB, PA, WH + 1ull * 691200, WL + 1ull * 691200, c2_bn);
  for (int i = 0; i < 2; ++i) {
    k_mconv<true><<<576, 256, 0, stream>>>(PA, PB, WH + (size_t)(2 + 2 * i) * 691200,
                                           WL + (size_t)(2 + 2 * i) * 691200, r3_bn + i * 1280);
    k_mconv<false><<<576, 256, 0, stream>>>(PB, PC, WH + (size_t)(3 + 2 * i) * 691200,
                                            WL + (size_t)(3 + 2 * i) * 691200,
                                            r3_bn + i * 1280 + 640);
    k_mean1<<<dim3(9, 8, 4), 256, 0, stream>>>(PC, YMP);
    k_mean2<<<6, 256, 0, stream>>>(YMP, YM);
    k_ca<<<1, 256, 0, stream>>>(YM, ca_w1 + i * 1600, ca_b1 + i * 10, ca_bn1 + i * 40,
                                ca_w2 + i * 1600, ca_b2 + i * 160, ca_bn2 + i * 640, Y2);
    k_sadd<<<23040, 256, 0, stream>>>(PA, PC, Y2);
  }
  k_mconv<true><<<576, 256, 0, stream>>>(PA, PB, WH + 6ull * 691200, WL + 6ull * 691200, c3_bn);
  k_c4<<<576, 256, 0, stream>>>(PB, c4_w, SC);
  k_out<<<16, 256, 0, stream>>>(SC, (float*)d_out);
}

// Round 5
// 2515.936 us; speedup vs baseline: 3.3603x; 1.0118x over previous
//
#include <hip/hip_runtime.h>
#include <hip/hip_bf16.h>
#include <math.h>

// ---------------- constants ----------------
constexpr float EPSB = 1e-5f;

// slice stage: channel-last padded [81][66][66][16] fp32
constexpr int SAS = 69696;         // slab stride (66*66*16)
constexpr int SRS = 1056;          // row stride (66*16)
constexpr size_t SVOL = 81ull * SAS;   // 5,645,376

// tower volume: [11][66][66][160] fp32 channel-last
constexpr int PZS = 696960;        // 4356*160
constexpr int PYS = 10560;         // 66*160
constexpr size_t PVOL = 11ull * 4356 * 160;  // 7,666,560

// workspace offsets (floats)
constexpr size_t OFF_SA   = 0;           // SVOL
constexpr size_t OFF_SB   = 5645376;     // SVOL
// PC (tower scratch) overlays SA/SB (dead by then): OFF_PC = 0
constexpr size_t OFF_MASK = 11290752;    // 81*4096
constexpr size_t OFF_INVM = 11622528;    // 4096
constexpr size_t OFF_SC   = 11626624;    // 36864
constexpr size_t OFF_YM   = 11663488;    // 1440
constexpr size_t OFF_Y2   = 11664928;    // 1440
constexpr size_t OFF_YMP  = 11666368;    // 46080
constexpr size_t OFF_PA   = 11712448;    // PVOL
constexpr size_t OFF_PB   = 19379008;    // PVOL -> end 27,045,568 floats
// ushort regions (element offsets from (ushort*)d_ws)
constexpr size_t UOFF_WH  = 54091136;            // 7*691200 tower hi
constexpr size_t UOFF_WL  = 58929536;            // 7*691200 tower lo
constexpr size_t UOFF_WSH = 63767936;            // 19*2560 slice hi
constexpr size_t UOFF_WSL = 63816576;            // 19*2560 slice lo
constexpr size_t UOFF_ABH = 63865216;            // 160*672 cost-B hi
constexpr size_t UOFF_ABL = 63972736;            // 160*672 cost-B lo

typedef short s16x8 __attribute__((ext_vector_type(8)));
typedef short s16x4 __attribute__((ext_vector_type(4)));
typedef float f32x4 __attribute__((ext_vector_type(4)));

__device__ __forceinline__ float lrelu_f(float v) { return v >= 0.f ? v : 0.1f * v; }
__device__ __forceinline__ float b2f(unsigned short s) {
  union { float f; unsigned u; } z; z.u = ((unsigned)s) << 16; return z.f;
}
__device__ __forceinline__ unsigned short f2b(float f) {
  __hip_bfloat16 h = __float2bfloat16(f);
  return *(unsigned short*)&h;
}

// ---------------- stage A: unshuffle + if0 conv + bn -> channel-last SA ----------------
__global__ __launch_bounds__(256) void k_if0(const float* __restrict__ x,
                                             const float* __restrict__ w0,
                                             const float* __restrict__ bn0,
                                             float* __restrict__ SA) {
  int a = blockIdx.x;
  int p = blockIdx.y * 256 + threadIdx.x;
  int y = p >> 6, xx = p & 63;
  int ai = a / 9, aj = a % 9;
  float v[3][3];
#pragma unroll
  for (int dy = 0; dy < 3; ++dy) {
    int gy = y + dy - 1;
#pragma unroll
    for (int dx = 0; dx < 3; ++dx) {
      int gx = xx + dx - 1;
      v[dy][dx] = (gy >= 0 && gy < 64 && gx >= 0 && gx < 64)
                      ? x[(ai * 64 + gy) * 576 + aj * 64 + gx] : 0.f;
    }
  }
  float o16[16];
#pragma unroll
  for (int c = 0; c < 16; ++c) {
    float acc = 0.f;
#pragma unroll
    for (int t = 0; t < 9; ++t) acc += w0[c * 9 + t] * v[t / 3][t % 3];
    float g = bn0[c], b = bn0[16 + c], m = bn0[32 + c], vv = bn0[48 + c];
    o16[c] = (acc - m) * (g * rsqrtf(vv + EPSB)) + b;
  }
  float* dst = SA + (size_t)a * SAS + (size_t)(y + 1) * SRS + (size_t)(xx + 1) * 16;
#pragma unroll
  for (int q = 0; q < 4; ++q)
    *(float4*)&dst[q * 4] = make_float4(o16[q*4], o16[q*4+1], o16[q*4+2], o16[q*4+3]);
}

// ---------------- slice weight transform: -> bf16 hi/lo [conv][co(16)][k=t*16+ci (160)] ----------------
__global__ __launch_bounds__(256) void k_wslice(const float* __restrict__ resb_w,
                                                const float* __restrict__ if1_w,
                                                const float* __restrict__ if2_w,
                                                const float* __restrict__ last_w,
                                                unsigned short* __restrict__ WSH,
                                                unsigned short* __restrict__ WSL) {
  int c = blockIdx.x;  // 0..18
  for (int idx = threadIdx.x; idx < 2560; idx += 256) {
    int o = idx / 160, k = idx % 160;
    int t = k >> 4, ci = k & 15;
    float v = 0.f;
    if (t < 9) {
      if (c < 16)       v = resb_w[((size_t)c * 256 + o * 16 + ci) * 9 + t];
      else if (c == 16) v = if1_w[(size_t)(o * 16 + ci) * 9 + t];
      else if (c == 17) v = (o < 8) ? if2_w[(size_t)(o * 16 + ci) * 9 + t] : 0.f;
      else              v = (o < 8 && ci < 8) ? last_w[(size_t)(o * 8 + ci) * 9 + t] : 0.f;
    }
    unsigned short h = f2b(v);
    WSH[c * 2560 + idx] = h;
    WSL[c * 2560 + idx] = f2b(v - b2f(h));
  }
}

// ---------------- tower weight transform (coalesced): [co][ci][27] -> hi/lo [t][co*160+ci] ----------------
__global__ __launch_bounds__(256) void k_wt7(const float* __restrict__ c1,
                                             const float* __restrict__ c2,
                                             const float* __restrict__ r3,
                                             const float* __restrict__ c3,
                                             unsigned short* __restrict__ WH,
                                             unsigned short* __restrict__ WL) {
  __shared__ float L[6912];
  int l = blockIdx.y;
  const float* w = (l == 0) ? c1 : (l == 1) ? c2 : (l < 6) ? r3 + (size_t)(l - 2) * 691200 : c3;
  size_t base = (size_t)blockIdx.x * 256;
  for (int i = threadIdx.x; i < 6912; i += 256) L[i] = w[base * 27 + i];
  __syncthreads();
  unsigned short* wh = WH + (size_t)l * 691200;
  unsigned short* wl = WL + (size_t)l * 691200;
  int r = (int)base + threadIdx.x;
#pragma unroll 1
  for (int t = 0; t < 27; ++t) {
    float v = L[threadIdx.x * 27 + t];
    unsigned short h = f2b(v);
    wh[(size_t)t * 25600 + r] = h;
    wl[(size_t)t * 25600 + r] = f2b(v - b2f(h));
  }
}

// ---------------- cost-B: (sq_w . fuse_w) -> bf16 hi/lo [o][k=uv*8+g (672)] ----------------
__global__ __launch_bounds__(192) void k_A(const float* __restrict__ sq_w,
                                           const float* __restrict__ fuse_w,
                                           unsigned short* __restrict__ ABH,
                                           unsigned short* __restrict__ ABL) {
  int k = blockIdx.x;  // 0..671
  int o = threadIdx.x;
  if (o >= 160) return;
  float acc = 0.f;
  if (k < 648) {
    int uv = k >> 3, g = k & 7;
    for (int o2 = 0; o2 < 64; ++o2)
      acc += sq_w[(size_t)o * 512 + g * 64 + o2] * fuse_w[(size_t)(g * 64 + o2) * 81 + uv];
  }
  unsigned short h = f2b(acc);
  ABH[(size_t)o * 672 + k] = h;
  ABL[(size_t)o * 672 + k] = f2b(acc - b2f(h));
}

// ---------------- mask generation ----------------
__device__ __forceinline__ float img_at(const float* __restrict__ x, int i, int j, int yy, int xx) {
  if (yy < 0 || yy >= 64 || xx < 0 || xx >= 64) return 0.f;
  return x[(i * 64 + yy) * 576 + j * 64 + xx];
}

__global__ __launch_bounds__(256) void k_mask(const float* __restrict__ x,
                                              const float* __restrict__ disp,
                                              float* __restrict__ mask,
                                              float* __restrict__ invm) {
  int p = blockIdx.x * 256 + threadIdx.x;
  int y = p >> 6, xx = p & 63;
  float d = -disp[p];
  float ref = x[(4 * 64 + y) * 576 + 4 * 64 + xx];
  float ssum = 0.f;
  float xbase = (float)xx * (64.0f / 63.0f);
  float ybase = (float)y * (64.0f / 63.0f);
  for (int i = 0; i < 9; ++i) {
    float py = ybase + (float)(i - 4) * d - 0.5f;
    float y0f = floorf(py);
    float fy = py - y0f;
    int y0 = (int)y0f;
    for (int j = 0; j < 9; ++j) {
      float px = xbase + (float)(j - 4) * d - 0.5f;
      float x0f = floorf(px);
      float fx = px - x0f;
      int x0 = (int)x0f;
      float val = img_at(x, i, j, y0, x0) * (1.f - fx) * (1.f - fy)
                + img_at(x, i, j, y0, x0 + 1) * fx * (1.f - fy)
                + img_at(x, i, j, y0 + 1, x0) * (1.f - fx) * fy
                + img_at(x, i, j, y0 + 1, x0 + 1) * fx * fy;
      float diff = (i == 4 && j == 4) ? 0.f : fabsf(val - ref);
      float m = 1.f - diff;
      m = m * m;
      mask[(i * 9 + j) * 4096 + p] = m;
      ssum += m;
    }
  }
  invm[p] = 81.f / ssum;
}

// ---------------- slice 3x3 conv, MFMA split-precision implicit GEMM ----------------
// in/out: channel-last padded [81][66][66][16] fp32. K = tap*16+ci (144 pad 160).
template <bool BN, bool LRELU, bool RESADD, int CO>
__global__ __launch_bounds__(256) void k_cs(const float* __restrict__ in,
                                            float* __restrict__ out,
                                            const unsigned short* __restrict__ wsh,
                                            const unsigned short* __restrict__ wsl,
                                            const float* __restrict__ bias,
                                            const float* __restrict__ bnp) {
  __shared__ short Ah[15840];   // [10 rows][66 px][24 shorts]
  __shared__ short Al[15840];
  int a = blockIdx.x, y0 = blockIdx.y * 8;
  int tid = threadIdx.x, lane = tid & 63, w = tid >> 6;
  int lr = lane & 15, lq = lane >> 4;
  const float* src = in + (size_t)a * SAS + (size_t)y0 * SRS;
  for (int it = tid; it < 2640; it += 256) {
    int row = it / 264, rem = it % 264;
    float4 f = *(const float4*)&src[row * SRS + rem * 4];
    int px = rem >> 2, q = rem & 3;
    s16x4 hv, lv;
    { unsigned short h = f2b(f.x); hv[0] = h; lv[0] = f2b(f.x - b2f(h)); }
    { unsigned short h = f2b(f.y); hv[1] = h; lv[1] = f2b(f.y - b2f(h)); }
    { unsigned short h = f2b(f.z); hv[2] = h; lv[2] = f2b(f.z - b2f(h)); }
    { unsigned short h = f2b(f.w); hv[3] = h; lv[3] = f2b(f.w - b2f(h)); }
    int base = (row * 66 + px) * 24 + q * 4;
    *(s16x4*)&Ah[base] = hv;
    *(s16x4*)&Al[base] = lv;
  }
  __syncthreads();
  s16x8 bh[5], bl[5];
#pragma unroll
  for (int ks = 0; ks < 5; ++ks) {
    bh[ks] = *(const s16x8*)&wsh[lr * 160 + ks * 32 + lq * 8];
    bl[ks] = *(const s16x8*)&wsl[lr * 160 + ks * 32 + lq * 8];
  }
  int offk[5];
#pragma unroll
  for (int ks = 0; ks < 5; ++ks) {
    int t = ks * 2 + (lq >> 1);
    if (t > 8) t = 8;  // k>=144: weights are zero; clamp keeps LDS read in-bounds/finite
    offk[ks] = ((t / 3) * 66 + (t % 3)) * 24 + (lq & 1) * 8;
  }
  f32x4 acc[8];
#pragma unroll
  for (int i = 0; i < 8; ++i) acc[i] = (f32x4){0.f, 0.f, 0.f, 0.f};
#pragma unroll
  for (int mf = 0; mf < 8; ++mf) {
    int gm = w * 8 + mf;
    int yl = gm >> 2, xq = gm & 3;
    int am = (yl * 66 + xq * 16 + lr) * 24;
#pragma unroll
    for (int ks = 0; ks < 5; ++ks) {
      s16x8 ah = *(const s16x8*)&Ah[am + offk[ks]];
      s16x8 al = *(const s16x8*)&Al[am + offk[ks]];
      acc[mf] = __builtin_amdgcn_mfma_f32_16x16x32_bf16(ah, bh[ks], acc[mf], 0, 0, 0);
      acc[mf] = __builtin_amdgcn_mfma_f32_16x16x32_bf16(ah, bl[ks], acc[mf], 0, 0, 0);
      acc[mf] = __builtin_amdgcn_mfma_f32_16x16x32_bf16(al, bh[ks], acc[mf], 0, 0, 0);
    }
  }
  int co = lr;
  bool coval = (CO == 16) || (co < CO);
  float sc = 1.f, sh = 0.f;
  if (BN && coval) {
    float g = bnp[co], b = bnp[CO + co], m = bnp[2 * CO + co], vv = bnp[3 * CO + co];
    sc = g * rsqrtf(vv + EPSB);
    sh = b - m * sc;
    if (bias) sh += bias[co] * sc;
  }
#pragma unroll
  for (int mf = 0; mf < 8; ++mf) {
    int gm = w * 8 + mf;
    int yl = gm >> 2, xq = gm & 3;
    if (coval) {
#pragma unroll
      for (int r = 0; r < 4; ++r) {
        int x = xq * 16 + lq * 4 + r;
        float val = acc[mf][r] * sc + sh;
        if (LRELU) val = lrelu_f(val);
        size_t oo = (size_t)a * SAS + (size_t)(y0 + yl + 1) * SRS + (size_t)(x + 1) * 16 + co;
        if (RESADD) out[oo] += val;
        else        out[oo] = val;
      }
    }
  }
}

// ---------------- fused cost volume + squeeze: MFMA split-precision ----------------
// M=64 (x row), N=160, K=672 (k=uv*8+g), 7 chunks of 96. Output -> PA fp32 padded.
__global__ __launch_bounds__(256) void k_costsq(const float* __restrict__ feat,
                                                const float* __restrict__ mask,
                                                const float* __restrict__ invm,
                                                const unsigned short* __restrict__ ABH,
                                                const unsigned short* __restrict__ ABL,
                                                const float* __restrict__ sq_bn,
                                                float* __restrict__ outPA) {
  __shared__ short Ah[6144];   // [64 x][96 k]
  __shared__ short Al[6144];
  int dI = blockIdx.x, y = blockIdx.y;
  int dd = dI - 4;
  int tid = threadIdx.x, lane = tid & 63, w = tid >> 6;
  int wm = w >> 1, wn = w & 1;
  int lr = lane & 15, lq = lane >> 4;
  f32x4 acc[2][5];
#pragma unroll
  for (int i = 0; i < 2; ++i)
#pragma unroll
    for (int j = 0; j < 5; ++j) acc[i][j] = (f32x4){0.f, 0.f, 0.f, 0.f};

  for (int ch = 0; ch < 7; ++ch) {
    __syncthreads();
    for (int it = tid; it < 768; it += 256) {
      int xl = it / 12, uvL = it % 12;
      int uv = ch * 12 + uvL;
      s16x8 hv = {0, 0, 0, 0, 0, 0, 0, 0}, lv = {0, 0, 0, 0, 0, 0, 0, 0};
      if (uv < 81) {
        int u = uv / 9, v = uv % 9;
        int ys = y + (4 - u) * dd;
        int xs = xl + (4 - v) * dd;
        if (ys >= 0 && ys < 64 && xs >= 0 && xs < 64) {
          const float* fp = feat + (size_t)uv * SAS + (size_t)(ys + 1) * SRS + (size_t)(xs + 1) * 16;
          float mv = mask[uv * 4096 + y * 64 + xl];
#pragma unroll
          for (int j = 0; j < 8; ++j) {
            float f = fp[j] * mv;
            unsigned short h = f2b(f);
            hv[j] = h;
            lv[j] = f2b(f - b2f(h));
          }
        }
      }
      *(s16x8*)&Ah[xl * 96 + uvL * 8] = hv;
      *(s16x8*)&Al[xl * 96 + uvL * 8] = lv;
    }
    __syncthreads();
#pragma unroll
    for (int kb = 0; kb < 3; ++kb) {
      int ka = kb * 32 + lq * 8;
      s16x8 a0h = *(const s16x8*)&Ah[(wm * 32 + lr) * 96 + ka];
      s16x8 a0l = *(const s16x8*)&Al[(wm * 32 + lr) * 96 + ka];
      s16x8 a1h = *(const s16x8*)&Ah[(wm * 32 + 16 + lr) * 96 + ka];
      s16x8 a1l = *(const s16x8*)&Al[(wm * 32 + 16 + lr) * 96 + ka];
      int kg = ch * 96 + ka;
#pragma unroll
      for (int nf = 0; nf < 5; ++nf) {
        int n = wn * 80 + nf * 16 + lr;
        s16x8 bh = *(const s16x8*)&ABH[(size_t)n * 672 + kg];
        s16x8 bl = *(const s16x8*)&ABL[(size_t)n * 672 + kg];
        acc[0][nf] = __builtin_amdgcn_mfma_f32_16x16x32_bf16(a0h, bh, acc[0][nf], 0, 0, 0);
        acc[0][nf] = __builtin_amdgcn_mfma_f32_16x16x32_bf16(a0h, bl, acc[0][nf], 0, 0, 0);
        acc[0][nf] = __builtin_amdgcn_mfma_f32_16x16x32_bf16(a0l, bh, acc[0][nf], 0, 0, 0);
        acc[1][nf] = __builtin_amdgcn_mfma_f32_16x16x32_bf16(a1h, bh, acc[1][nf], 0, 0, 0);
        acc[1][nf] = __builtin_amdgcn_mfma_f32_16x16x32_bf16(a1h, bl, acc[1][nf], 0, 0, 0);
        acc[1][nf] = __builtin_amdgcn_mfma_f32_16x16x32_bf16(a1l, bh, acc[1][nf], 0, 0, 0);
      }
    }
  }
#pragma unroll
  for (int nf = 0; nf < 5; ++nf) {
    int n = wn * 80 + nf * 16 + lr;
    float g = sq_bn[n], b = sq_bn[160 + n], m = sq_bn[320 + n], vv = sq_bn[480 + n];
    float sc = g * rsqrtf(vv + EPSB), sh = b - m * sc;
#pragma unroll
    for (int mf = 0; mf < 2; ++mf) {
#pragma unroll
      for (int r = 0; r < 4; ++r) {
        int x = wm * 32 + mf * 16 + lq * 4 + r;
        float val = acc[mf][nf][r] * invm[y * 64 + x];
        val = val * sc + sh;
        val = lrelu_f(val);
        outPA[(size_t)(dI + 1) * PZS + (size_t)(y + 1) * PYS + (size_t)(x + 1) * 160 + n] = val;
      }
    }
  }
}

// ---------------- tower: MFMA split-precision 3x3x3 conv 160->160 ----------------
// T14 async-STAGE: next plane prefetched to registers before the MFMA phase.
template <bool LRELU>
__global__ __launch_bounds__(256, 3) void k_mconv(const float* __restrict__ in,
                                                  float* __restrict__ out,
                                                  const unsigned short* __restrict__ wh,
                                                  const unsigned short* __restrict__ wl,
                                                  const float* __restrict__ bnp) {
  __shared__ short Ah[66 * 168];
  __shared__ short Al[66 * 168];
  int zy = blockIdx.x;
  int z = zy / 64, y = zy % 64;
  int tid = threadIdx.x;
  int lane = tid & 63;
  int wave = tid >> 6;
  int wm = wave >> 1, wn = wave & 1;
  int lr = lane & 15;
  int lq = lane >> 4;

  f32x4 acc[2][5];
#pragma unroll
  for (int i = 0; i < 2; ++i)
#pragma unroll
    for (int j = 0; j < 5; ++j) acc[i][j] = (f32x4){0.f, 0.f, 0.f, 0.f};

  // prologue: prefetch plane 0 (dz=0, dy=0) to registers
  float4 pf[11];
  {
    const float* src = in + (size_t)z * PZS + (size_t)y * PYS;
#pragma unroll
    for (int j = 0; j < 11; ++j) {
      int v = tid + 256 * j;
      if (v < 2640) pf[j] = *(const float4*)&src[v * 4];
    }
  }

#pragma unroll 1
  for (int dzy = 0; dzy < 9; ++dzy) {
    __syncthreads();  // previous MFMA phase done reading LDS
    // convert prefetched plane -> LDS hi/lo
#pragma unroll
    for (int j = 0; j < 11; ++j) {
      int v = tid + 256 * j;
      if (v < 2640) {
        float4 f = pf[j];
        int row = v / 40, col = (v % 40) * 4;
        s16x4 hv, lv;
        { unsigned short h = f2b(f.x); hv[0] = h; lv[0] = f2b(f.x - b2f(h)); }
        { unsigned short h = f2b(f.y); hv[1] = h; lv[1] = f2b(f.y - b2f(h)); }
        { unsigned short h = f2b(f.z); hv[2] = h; lv[2] = f2b(f.z - b2f(h)); }
        { unsigned short h = f2b(f.w); hv[3] = h; lv[3] = f2b(f.w - b2f(h)); }
        *(s16x4*)&Ah[row * 168 + col] = hv;
        *(s16x4*)&Al[row * 168 + col] = lv;
      }
    }
    __syncthreads();
    // issue next plane's loads NOW; latency hides under the MFMA phase below
    if (dzy < 8) {
      int dz = (dzy + 1) / 3, dy = (dzy + 1) % 3;
      const float* src = in + (size_t)(z + dz) * PZS + (size_t)(y + dy) * PYS;
#pragma unroll
      for (int j = 0; j < 11; ++j) {
        int v = tid + 256 * j;
        if (v < 2640) pf[j] = *(const float4*)&src[v * 4];
      }
    }
    // MFMA phase for current plane (3 dx taps)
#pragma unroll 1
    for (int dx = 0; dx < 3; ++dx) {
      const unsigned short* wht = wh + (size_t)(dzy * 3 + dx) * 25600;
      const unsigned short* wlt = wl + (size_t)(dzy * 3 + dx) * 25600;
#pragma unroll
      for (int ks = 0; ks < 5; ++ks) {
        int r0 = (wm * 32 + lr + dx) * 168 + ks * 32 + lq * 8;
        int r1 = (wm * 32 + 16 + lr + dx) * 168 + ks * 32 + lq * 8;
        s16x8 a0h = *(const s16x8*)&Ah[r0];
        s16x8 a1h = *(const s16x8*)&Ah[r1];
        s16x8 a0l = *(const s16x8*)&Al[r0];
        s16x8 a1l = *(const s16x8*)&Al[r1];
#pragma unroll
        for (int nf = 0; nf < 5; ++nf) {
          size_t wo = (size_t)(wn * 80 + nf * 16 + lr) * 160 + ks * 32 + lq * 8;
          s16x8 bh = *(const s16x8*)&wht[wo];
          s16x8 bl = *(const s16x8*)&wlt[wo];
          acc[0][nf] = __builtin_amdgcn_mfma_f32_16x16x32_bf16(a0h, bh, acc[0][nf], 0, 0, 0);
          acc[0][nf] = __builtin_amdgcn_mfma_f32_16x16x32_bf16(a0h, bl, acc[0][nf], 0, 0, 0);
          acc[0][nf] = __builtin_amdgcn_mfma_f32_16x16x32_bf16(a0l, bh, acc[0][nf], 0, 0, 0);
          acc[1][nf] = __builtin_amdgcn_mfma_f32_16x16x32_bf16(a1h, bh, acc[1][nf], 0, 0, 0);
          acc[1][nf] = __builtin_amdgcn_mfma_f32_16x16x32_bf16(a1h, bl, acc[1][nf], 0, 0, 0);
          acc[1][nf] = __builtin_amdgcn_mfma_f32_16x16x32_bf16(a1l, bh, acc[1][nf], 0, 0, 0);
        }
      }
    }
  }
#pragma unroll
  for (int nf = 0; nf < 5; ++nf) {
    int n = wn * 80 + nf * 16 + lr;
    float sc = bnp[n] * rsqrtf(bnp[480 + n] + EPSB);
    float sh = bnp[160 + n] - bnp[320 + n] * sc;
#pragma unroll
    for (int mf = 0; mf < 2; ++mf) {
#pragma unroll
      for (int r = 0; r < 4; ++r) {
        int m = wm * 32 + mf * 16 + lq * 4 + r;
        float val = acc[mf][nf][r] * sc + sh;
        if (LRELU) val = lrelu_f(val);
        out[(size_t)(z + 1) * PZS + (size_t)(y + 1) * PYS + (size_t)(m + 1) * 160 + n] = val;
      }
    }
  }
}

// ---------------- c4: 160 -> 1 conv (fp32) ----------------
__global__ __launch_bounds__(256) void k_c4(const float* __restrict__ in,
                                            const float* __restrict__ w,
                                            float* __restrict__ score) {
  __shared__ float L[66 * 169];
  __shared__ float red[256];
  int zy = blockIdx.x;
  int z = zy / 64, y = zy % 64;
  int tid = threadIdx.x;
  int x = tid & 63, q = tid >> 6;
  float acc = 0.f;
  for (int dzy = 0; dzy < 9; ++dzy) {
    int dz = dzy / 3, dy = dzy % 3;
    const float* src = in + (size_t)(z + dz) * PZS + (size_t)(y + dy) * PYS;
    __syncthreads();
    for (int v = tid; v < 10560; v += 256) {
      int row = v / 160, col = v % 160;
      L[row * 169 + col] = src[v];
    }
    __syncthreads();
#pragma unroll 1
    for (int dx = 0; dx < 3; ++dx) {
      int t = dzy * 3 + dx;
      for (int ci = q * 40; ci < q * 40 + 40; ++ci)
        acc += L[(x + dx) * 169 + ci] * w[ci * 27 + t];
    }
  }
  red[tid] = acc;
  __syncthreads();
  if (q == 0)
    score[z * 4096 + y * 64 + x] = red[x] + red[64 + x] + red[128 + x] + red[192 + x];
}

// ---------------- channel attention ----------------
__global__ __launch_bounds__(256) void k_mean1(const float* __restrict__ in,
                                               float* __restrict__ ymp) {
  int z = blockIdx.x, yg = blockIdx.y, xq = blockIdx.z;
  int c = threadIdx.x;
  if (c >= 160) return;
  float s = 0.f;
  for (int yy = 0; yy < 8; ++yy) {
    int y = yg * 8 + yy;
    for (int xl = 0; xl < 16; ++xl) {
      int x = xq * 16 + xl;
      s += in[(size_t)(z + 1) * PZS + (size_t)(y + 1) * PYS + (size_t)(x + 1) * 160 + c];
    }
  }
  ymp[((z * 8 + yg) * 4 + xq) * 160 + c] = s;
}

__global__ __launch_bounds__(256) void k_mean2(const float* __restrict__ ymp,
                                               float* __restrict__ ym) {
  int idx = blockIdx.x * 256 + threadIdx.x;
  if (idx >= 1440) return;
  int c = idx / 9, z = idx % 9;
  float s = 0.f;
  for (int p = 0; p < 32; ++p) s += ymp[(z * 32 + p) * 160 + c];
  ym[idx] = s * (1.f / 4096.f);
}

__global__ __launch_bounds__(256) void k_ca(const float* __restrict__ ym,
                                            const float* __restrict__ w1,
                                            const float* __restrict__ b1,
                                            const float* __restrict__ bn1,
                                            const float* __restrict__ w2,
                                            const float* __restrict__ b2,
                                            const float* __restrict__ bn2,
                                            float* __restrict__ y2) {
  __shared__ float yml[1440];
  __shared__ float yy[90];
  for (int i = threadIdx.x; i < 1440; i += 256) yml[i] = ym[i];
  __syncthreads();
  if (threadIdx.x < 90) {
    int c = threadIdx.x / 9, z = threadIdx.x % 9;
    float acc = b1[c];
    for (int ci = 0; ci < 160; ++ci) acc += w1[c * 160 + ci] * yml[ci * 9 + z];
    float g = bn1[c], b = bn1[10 + c], m = bn1[20 + c], vv = bn1[30 + c];
    acc = (acc - m) * (g * rsqrtf(vv + EPSB)) + b;
    yy[threadIdx.x] = lrelu_f(acc);
  }
  __syncthreads();
  for (int i = threadIdx.x; i < 1440; i += 256) {
    int c = i / 9, z = i % 9;
    float acc = b2[c];
#pragma unroll
    for (int k = 0; k < 10; ++k) acc += w2[c * 10 + k] * yy[k * 9 + z];
    float g = bn2[c], b = bn2[160 + c], m = bn2[320 + c], vv = bn2[480 + c];
    acc = (acc - m) * (g * rsqrtf(vv + EPSB)) + b;
    y2[i] = 1.f / (1.f + expf(-acc));
  }
}

__global__ __launch_bounds__(256) void k_sadd(float* __restrict__ buf,
                                              const float* __restrict__ t,
                                              const float* __restrict__ y2) {
  int i = blockIdx.x * 256 + threadIdx.x;
  int p = i / 160, c = i % 160;
  int z = p >> 12, r = p & 4095;
  int y = r >> 6, x = r & 63;
  size_t a = (size_t)(z + 1) * PZS + (size_t)(y + 1) * PYS + (size_t)(x + 1) * 160 + c;
  buf[a] += t[a] * y2[c * 9 + z];
}

// ---------------- softmax + expectation ----------------
__global__ __launch_bounds__(256) void k_out(const float* __restrict__ score,
                                             float* __restrict__ out) {
  int p = blockIdx.x * 256 + threadIdx.x;
  float v[9];
  float mx = -1e30f;
#pragma unroll
  for (int z = 0; z < 9; ++z) {
    v[z] = score[z * 4096 + p];
    mx = fmaxf(mx, v[z]);
  }
  float s = 0.f, r = 0.f;
#pragma unroll
  for (int z = 0; z < 9; ++z) {
    float e = expf(v[z] - mx);
    s += e;
    r += e * (float)(z - 4);
  }
  out[p] = r / s;
}

// ---------------- launch ----------------
extern "C" void kernel_launch(void* const* d_in, const int* in_sizes, int n_in,
                              void* d_out, int out_size, void* d_ws, size_t ws_size,
                              hipStream_t stream) {
  const float* X      = (const float*)d_in[0];
  const float* disp   = (const float*)d_in[1];
  const float* if_w0  = (const float*)d_in[2];
  const float* if_bn0 = (const float*)d_in[3];
  const float* resb_w = (const float*)d_in[4];
  const float* resb_b = (const float*)d_in[5];
  const float* resb_bn= (const float*)d_in[6];
  const float* if_w1  = (const float*)d_in[7];
  const float* if_bn1 = (const float*)d_in[8];
  const float* if_w2  = (const float*)d_in[9];
  const float* if_bn2 = (const float*)d_in[10];
  const float* last_w = (const float*)d_in[11];
  const float* fuse_w = (const float*)d_in[12];
  const float* sq_w   = (const float*)d_in[13];
  const float* sq_bn  = (const float*)d_in[14];
  const float* c1_w   = (const float*)d_in[15];
  const float* c1_bn  = (const float*)d_in[16];
  const float* c2_w   = (const float*)d_in[17];
  const float* c2_bn  = (const float*)d_in[18];
  const float* c3_w   = (const float*)d_in[19];
  const float* c3_bn  = (const float*)d_in[20];
  const float* c4_w   = (const float*)d_in[21];
  const float* r3_w   = (const float*)d_in[22];
  const float* r3_bn  = (const float*)d_in[23];
  const float* ca_w1  = (const float*)d_in[24];
  const float* ca_b1  = (const float*)d_in[25];
  const float* ca_bn1 = (const float*)d_in[26];
  const float* ca_w2  = (const float*)d_in[27];
  const float* ca_b2  = (const float*)d_in[28];
  const float* ca_bn2 = (const float*)d_in[29];

  float* ws   = (float*)d_ws;
  float* SA   = ws + OFF_SA;
  float* SB   = ws + OFF_SB;
  float* PC   = ws;               // overlays SA/SB (dead after costsq)
  float* MASK = ws + OFF_MASK;
  float* INVM = ws + OFF_INVM;
  float* SC   = ws + OFF_SC;
  float* YM   = ws + OFF_YM;
  float* Y2   = ws + OFF_Y2;
  float* YMP  = ws + OFF_YMP;
  float* PA   = ws + OFF_PA;
  float* PB   = ws + OFF_PB;
  unsigned short* U   = (unsigned short*)d_ws;
  unsigned short* WH  = U + UOFF_WH;
  unsigned short* WL  = U + UOFF_WL;
  unsigned short* WSH = U + UOFF_WSH;
  unsigned short* WSL = U + UOFF_WSL;
  unsigned short* ABH = U + UOFF_ABH;
  unsigned short* ABL = U + UOFF_ABL;

  hipMemsetAsync(SA, 0, SVOL * 4, stream);
  hipMemsetAsync(SB, 0, SVOL * 4, stream);
  hipMemsetAsync(PA, 0, PVOL * 4, stream);
  hipMemsetAsync(PB, 0, PVOL * 4, stream);

  k_wt7<<<dim3(100, 7), 256, 0, stream>>>(c1_w, c2_w, r3_w, c3_w, WH, WL);
  k_wslice<<<19, 256, 0, stream>>>(resb_w, if_w1, if_w2, last_w, WSH, WSL);
  k_A<<<672, 192, 0, stream>>>(sq_w, fuse_w, ABH, ABL);
  k_mask<<<16, 256, 0, stream>>>(X, disp, MASK, INVM);

  k_if0<<<dim3(81, 16), 256, 0, stream>>>(X, if_w0, if_bn0, SA);
  for (int i = 0; i < 8; ++i) {
    k_cs<true, true, false, 16><<<dim3(81, 8), 256, 0, stream>>>(
        SA, SB, WSH + (size_t)(2 * i) * 2560, WSL + (size_t)(2 * i) * 2560,
        resb_b + i * 32, resb_bn + i * 128);
    k_cs<true, false, true, 16><<<dim3(81, 8), 256, 0, stream>>>(
        SB, SA, WSH + (size_t)(2 * i + 1) * 2560, WSL + (size_t)(2 * i + 1) * 2560,
        resb_b + i * 32 + 16, resb_bn + i * 128 + 64);
  }
  k_cs<true, true, false, 16><<<dim3(81, 8), 256, 0, stream>>>(
      SA, SB, WSH + 16 * 2560, WSL + 16 * 2560, nullptr, if_bn1);
  k_cs<true, true, false, 8><<<dim3(81, 8), 256, 0, stream>>>(
      SB, SA, WSH + 17 * 2560, WSL + 17 * 2560, nullptr, if_bn2);
  k_cs<false, false, false, 8><<<dim3(81, 8), 256, 0, stream>>>(
      SA, SB, WSH + 18 * 2560, WSL + 18 * 2560, nullptr, nullptr);

  k_costsq<<<dim3(9, 64), 256, 0, stream>>>(SB, MASK, INVM, ABH, ABL, sq_bn, PA);
  hipMemsetAsync(PC, 0, PVOL * 4, stream);  // SA/SB dead; PC borders must be zero

  k_mconv<true><<<576, 256, 0, stream>>>(PA, PB, WH + 0ull * 691200, WL + 0ull * 691200, c1_bn);
  k_mconv<true><<<576, 256, 0, stream>>>(PB, PA, WH + 1ull * 691200, WL + 1ull * 691200, c2_bn);
  for (int i = 0; i < 2; ++i) {
    k_mconv<true><<<576, 256, 0, stream>>>(PA, PB, WH + (size_t)(2 + 2 * i) * 691200,
                                           WL + (size_t)(2 + 2 * i) * 691200, r3_bn + i * 1280);
    k_mconv<false><<<576, 256, 0, stream>>>(PB, PC, WH + (size_t)(3 + 2 * i) * 691200,
                                            WL + (size_t)(3 + 2 * i) * 691200,
                                            r3_bn + i * 1280 + 640);
    k_mean1<<<dim3(9, 8, 4), 256, 0, stream>>>(PC, YMP);
    k_mean2<<<6, 256, 0, stream>>>(YMP, YM);
    k_ca<<<1, 256, 0, stream>>>(YM, ca_w1 + i * 1600, ca_b1 + i * 10, ca_bn1 + i * 40,
                                ca_w2 + i * 1600, ca_b2 + i * 160, ca_bn2 + i * 640, Y2);
    k_sadd<<<23040, 256, 0, stream>>>(PA, PC, Y2);
  }
  k_mconv<true><<<576, 256, 0, stream>>>(PA, PB, WH + 6ull * 691200, WL + 6ull * 691200, c3_bn);
  k_c4<<<576, 256, 0, stream>>>(PB, c4_w, SC);
  k_out<<<16, 256, 0, stream>>>(SC, (float*)d_out);
}

// Round 7
// 1709.280 us; speedup vs baseline: 4.9461x; 1.4719x over previous
//
#include <hip/hip_runtime.h>
#include <hip/hip_bf16.h>
#include <math.h>

// ---------------- constants ----------------
constexpr float EPSB = 1e-5f;

// slice stage: channel-last padded [81][66][66][16] fp32
constexpr int SAS = 69696;         // slab stride (66*66*16)
constexpr int SRS = 1056;          // row stride (66*16)
constexpr size_t SVOL = 81ull * SAS;   // 5,645,376

// tower volume: [11][66][66][160] fp32 channel-last
constexpr int PZS = 696960;        // 4356*160
constexpr int PYS = 10560;         // 66*160
constexpr size_t PVOL = 11ull * 4356 * 160;  // 7,666,560

// workspace offsets (floats)
constexpr size_t OFF_SA   = 0;           // SVOL
constexpr size_t OFF_SB   = 5645376;     // SVOL
// PC (tower scratch) overlays SA/SB (dead by then): OFF_PC = 0
constexpr size_t OFF_MASK = 11290752;    // 81*4096
constexpr size_t OFF_INVM = 11622528;    // 4096
constexpr size_t OFF_SC   = 11626624;    // 36864
constexpr size_t OFF_YM   = 11663488;    // 1440
constexpr size_t OFF_Y2   = 11664928;    // 1440
constexpr size_t OFF_YMP  = 11666368;    // 46080
constexpr size_t OFF_PA   = 11712448;    // PVOL
constexpr size_t OFF_PB   = 19379008;    // PVOL -> end 27,045,568 floats
// ushort regions (element offsets from (ushort*)d_ws)
constexpr size_t UOFF_WH  = 54091136;            // 7*691200 tower weights (fp16 now)
constexpr size_t UOFF_WSH = 63767936;            // 19*2560 slice hi
constexpr size_t UOFF_WSL = 63816576;            // 19*2560 slice lo
constexpr size_t UOFF_ABH = 63865216;            // 160*672 cost-B hi
constexpr size_t UOFF_ABL = 63972736;            // 160*672 cost-B lo

typedef short s16x8 __attribute__((ext_vector_type(8)));
typedef short s16x4 __attribute__((ext_vector_type(4)));
typedef float f32x4 __attribute__((ext_vector_type(4)));
typedef _Float16 h16x8 __attribute__((ext_vector_type(8)));
typedef _Float16 h16x4 __attribute__((ext_vector_type(4)));

__device__ __forceinline__ float lrelu_f(float v) { return v >= 0.f ? v : 0.1f * v; }
__device__ __forceinline__ float b2f(unsigned short s) {
  union { float f; unsigned u; } z; z.u = ((unsigned)s) << 16; return z.f;
}
__device__ __forceinline__ unsigned short f2b(float f) {
  __hip_bfloat16 h = __float2bfloat16(f);
  return *(unsigned short*)&h;
}

// ---------------- stage A: unshuffle + if0 conv + bn -> channel-last SA ----------------
__global__ __launch_bounds__(256) void k_if0(const float* __restrict__ x,
                                             const float* __restrict__ w0,
                                             const float* __restrict__ bn0,
                                             float* __restrict__ SA) {
  int a = blockIdx.x;
  int p = blockIdx.y * 256 + threadIdx.x;
  int y = p >> 6, xx = p & 63;
  int ai = a / 9, aj = a % 9;
  float v[3][3];
#pragma unroll
  for (int dy = 0; dy < 3; ++dy) {
    int gy = y + dy - 1;
#pragma unroll
    for (int dx = 0; dx < 3; ++dx) {
      int gx = xx + dx - 1;
      v[dy][dx] = (gy >= 0 && gy < 64 && gx >= 0 && gx < 64)
                      ? x[(ai * 64 + gy) * 576 + aj * 64 + gx] : 0.f;
    }
  }
  float o16[16];
#pragma unroll
  for (int c = 0; c < 16; ++c) {
    float acc = 0.f;
#pragma unroll
    for (int t = 0; t < 9; ++t) acc += w0[c * 9 + t] * v[t / 3][t % 3];
    float g = bn0[c], b = bn0[16 + c], m = bn0[32 + c], vv = bn0[48 + c];
    o16[c] = (acc - m) * (g * rsqrtf(vv + EPSB)) + b;
  }
  float* dst = SA + (size_t)a * SAS + (size_t)(y + 1) * SRS + (size_t)(xx + 1) * 16;
#pragma unroll
  for (int q = 0; q < 4; ++q)
    *(float4*)&dst[q * 4] = make_float4(o16[q*4], o16[q*4+1], o16[q*4+2], o16[q*4+3]);
}

// ---------------- slice weight transform: -> bf16 hi/lo [conv][co(16)][k=t*16+ci (160)] ----------------
__global__ __launch_bounds__(256) void k_wslice(const float* __restrict__ resb_w,
                                                const float* __restrict__ if1_w,
                                                const float* __restrict__ if2_w,
                                                const float* __restrict__ last_w,
                                                unsigned short* __restrict__ WSH,
                                                unsigned short* __restrict__ WSL) {
  int c = blockIdx.x;  // 0..18
  for (int idx = threadIdx.x; idx < 2560; idx += 256) {
    int o = idx / 160, k = idx % 160;
    int t = k >> 4, ci = k & 15;
    float v = 0.f;
    if (t < 9) {
      if (c < 16)       v = resb_w[((size_t)c * 256 + o * 16 + ci) * 9 + t];
      else if (c == 16) v = if1_w[(size_t)(o * 16 + ci) * 9 + t];
      else if (c == 17) v = (o < 8) ? if2_w[(size_t)(o * 16 + ci) * 9 + t] : 0.f;
      else              v = (o < 8 && ci < 8) ? last_w[(size_t)(o * 8 + ci) * 9 + t] : 0.f;
    }
    unsigned short h = f2b(v);
    WSH[c * 2560 + idx] = h;
    WSL[c * 2560 + idx] = f2b(v - b2f(h));
  }
}

// ---------------- tower weight transform (coalesced): [co][ci][27] -> fp16 [t][co*160+ci] ----------------
__global__ __launch_bounds__(256) void k_wt7(const float* __restrict__ c1,
                                             const float* __restrict__ c2,
                                             const float* __restrict__ r3,
                                             const float* __restrict__ c3,
                                             _Float16* __restrict__ WH) {
  __shared__ float L[6912];
  int l = blockIdx.y;
  const float* w = (l == 0) ? c1 : (l == 1) ? c2 : (l < 6) ? r3 + (size_t)(l - 2) * 691200 : c3;
  size_t base = (size_t)blockIdx.x * 256;
  for (int i = threadIdx.x; i < 6912; i += 256) L[i] = w[base * 27 + i];
  __syncthreads();
  _Float16* wh = WH + (size_t)l * 691200;
  int r = (int)base + threadIdx.x;
#pragma unroll 1
  for (int t = 0; t < 27; ++t) {
    float v = L[threadIdx.x * 27 + t];
    wh[(size_t)t * 25600 + r] = (_Float16)v;
  }
}

// ---------------- cost-B: (sq_w . fuse_w) -> bf16 hi/lo [o][k=uv*8+g (672)] ----------------
__global__ __launch_bounds__(192) void k_A(const float* __restrict__ sq_w,
                                           const float* __restrict__ fuse_w,
                                           unsigned short* __restrict__ ABH,
                                           unsigned short* __restrict__ ABL) {
  int k = blockIdx.x;  // 0..671
  int o = threadIdx.x;
  if (o >= 160) return;
  float acc = 0.f;
  if (k < 648) {
    int uv = k >> 3, g = k & 7;
    for (int o2 = 0; o2 < 64; ++o2)
      acc += sq_w[(size_t)o * 512 + g * 64 + o2] * fuse_w[(size_t)(g * 64 + o2) * 81 + uv];
  }
  unsigned short h = f2b(acc);
  ABH[(size_t)o * 672 + k] = h;
  ABL[(size_t)o * 672 + k] = f2b(acc - b2f(h));
}

// ---------------- mask generation ----------------
__device__ __forceinline__ float img_at(const float* __restrict__ x, int i, int j, int yy, int xx) {
  if (yy < 0 || yy >= 64 || xx < 0 || xx >= 64) return 0.f;
  return x[(i * 64 + yy) * 576 + j * 64 + xx];
}

__global__ __launch_bounds__(256) void k_mask(const float* __restrict__ x,
                                              const float* __restrict__ disp,
                                              float* __restrict__ mask,
                                              float* __restrict__ invm) {
  int p = blockIdx.x * 256 + threadIdx.x;
  int y = p >> 6, xx = p & 63;
  float d = -disp[p];
  float ref = x[(4 * 64 + y) * 576 + 4 * 64 + xx];
  float ssum = 0.f;
  float xbase = (float)xx * (64.0f / 63.0f);
  float ybase = (float)y * (64.0f / 63.0f);
  for (int i = 0; i < 9; ++i) {
    float py = ybase + (float)(i - 4) * d - 0.5f;
    float y0f = floorf(py);
    float fy = py - y0f;
    int y0 = (int)y0f;
    for (int j = 0; j < 9; ++j) {
      float px = xbase + (float)(j - 4) * d - 0.5f;
      float x0f = floorf(px);
      float fx = px - x0f;
      int x0 = (int)x0f;
      float val = img_at(x, i, j, y0, x0) * (1.f - fx) * (1.f - fy)
                + img_at(x, i, j, y0, x0 + 1) * fx * (1.f - fy)
                + img_at(x, i, j, y0 + 1, x0) * (1.f - fx) * fy
                + img_at(x, i, j, y0 + 1, x0 + 1) * fx * fy;
      float diff = (i == 4 && j == 4) ? 0.f : fabsf(val - ref);
      float m = 1.f - diff;
      m = m * m;
      mask[(i * 9 + j) * 4096 + p] = m;
      ssum += m;
    }
  }
  invm[p] = 81.f / ssum;
}

// ---------------- slice 3x3 conv, MFMA split-precision implicit GEMM ----------------
// in/out: channel-last padded [81][66][66][16] fp32. K = tap*16+ci (144 pad 160).
template <bool BN, bool LRELU, bool RESADD, int CO>
__global__ __launch_bounds__(256) void k_cs(const float* __restrict__ in,
                                            float* __restrict__ out,
                                            const unsigned short* __restrict__ wsh,
                                            const unsigned short* __restrict__ wsl,
                                            const float* __restrict__ bias,
                                            const float* __restrict__ bnp) {
  __shared__ short Ah[15840];   // [10 rows][66 px][24 shorts]
  __shared__ short Al[15840];
  int a = blockIdx.x, y0 = blockIdx.y * 8;
  int tid = threadIdx.x, lane = tid & 63, w = tid >> 6;
  int lr = lane & 15, lq = lane >> 4;
  const float* src = in + (size_t)a * SAS + (size_t)y0 * SRS;
  for (int it = tid; it < 2640; it += 256) {
    int row = it / 264, rem = it % 264;
    float4 f = *(const float4*)&src[row * SRS + rem * 4];
    int px = rem >> 2, q = rem & 3;
    s16x4 hv, lv;
    { unsigned short h = f2b(f.x); hv[0] = h; lv[0] = f2b(f.x - b2f(h)); }
    { unsigned short h = f2b(f.y); hv[1] = h; lv[1] = f2b(f.y - b2f(h)); }
    { unsigned short h = f2b(f.z); hv[2] = h; lv[2] = f2b(f.z - b2f(h)); }
    { unsigned short h = f2b(f.w); hv[3] = h; lv[3] = f2b(f.w - b2f(h)); }
    int base = (row * 66 + px) * 24 + q * 4;
    *(s16x4*)&Ah[base] = hv;
    *(s16x4*)&Al[base] = lv;
  }
  __syncthreads();
  s16x8 bh[5], bl[5];
#pragma unroll
  for (int ks = 0; ks < 5; ++ks) {
    bh[ks] = *(const s16x8*)&wsh[lr * 160 + ks * 32 + lq * 8];
    bl[ks] = *(const s16x8*)&wsl[lr * 160 + ks * 32 + lq * 8];
  }
  int offk[5];
#pragma unroll
  for (int ks = 0; ks < 5; ++ks) {
    int t = ks * 2 + (lq >> 1);
    if (t > 8) t = 8;  // k>=144: weights are zero; clamp keeps LDS read in-bounds/finite
    offk[ks] = ((t / 3) * 66 + (t % 3)) * 24 + (lq & 1) * 8;
  }
  f32x4 acc[8];
#pragma unroll
  for (int i = 0; i < 8; ++i) acc[i] = (f32x4){0.f, 0.f, 0.f, 0.f};
#pragma unroll
  for (int mf = 0; mf < 8; ++mf) {
    int gm = w * 8 + mf;
    int yl = gm >> 2, xq = gm & 3;
    int am = (yl * 66 + xq * 16 + lr) * 24;
#pragma unroll
    for (int ks = 0; ks < 5; ++ks) {
      s16x8 ah = *(const s16x8*)&Ah[am + offk[ks]];
      s16x8 al = *(const s16x8*)&Al[am + offk[ks]];
      acc[mf] = __builtin_amdgcn_mfma_f32_16x16x32_bf16(ah, bh[ks], acc[mf], 0, 0, 0);
      acc[mf] = __builtin_amdgcn_mfma_f32_16x16x32_bf16(ah, bl[ks], acc[mf], 0, 0, 0);
      acc[mf] = __builtin_amdgcn_mfma_f32_16x16x32_bf16(al, bh[ks], acc[mf], 0, 0, 0);
    }
  }
  int co = lr;
  bool coval = (CO == 16) || (co < CO);
  float sc = 1.f, sh = 0.f;
  if (BN && coval) {
    float g = bnp[co], b = bnp[CO + co], m = bnp[2 * CO + co], vv = bnp[3 * CO + co];
    sc = g * rsqrtf(vv + EPSB);
    sh = b - m * sc;
    if (bias) sh += bias[co] * sc;
  }
#pragma unroll
  for (int mf = 0; mf < 8; ++mf) {
    int gm = w * 8 + mf;
    int yl = gm >> 2, xq = gm & 3;
    if (coval) {
#pragma unroll
      for (int r = 0; r < 4; ++r) {
        int x = xq * 16 + lq * 4 + r;
        float val = acc[mf][r] * sc + sh;
        if (LRELU) val = lrelu_f(val);
        size_t oo = (size_t)a * SAS + (size_t)(y0 + yl + 1) * SRS + (size_t)(x + 1) * 16 + co;
        if (RESADD) out[oo] += val;
        else        out[oo] = val;
      }
    }
  }
}

// ---------------- fused cost volume + squeeze: MFMA split-precision ----------------
// M=64 (x row), N=160, K=672 (k=uv*8+g), 7 chunks of 96. Output -> PA fp32 padded.
__global__ __launch_bounds__(256) void k_costsq(const float* __restrict__ feat,
                                                const float* __restrict__ mask,
                                                const float* __restrict__ invm,
                                                const unsigned short* __restrict__ ABH,
                                                const unsigned short* __restrict__ ABL,
                                                const float* __restrict__ sq_bn,
                                                float* __restrict__ outPA) {
  __shared__ short Ah[6144];   // [64 x][96 k]
  __shared__ short Al[6144];
  int dI = blockIdx.x, y = blockIdx.y;
  int dd = dI - 4;
  int tid = threadIdx.x, lane = tid & 63, w = tid >> 6;
  int wm = w >> 1, wn = w & 1;
  int lr = lane & 15, lq = lane >> 4;
  f32x4 acc[2][5];
#pragma unroll
  for (int i = 0; i < 2; ++i)
#pragma unroll
    for (int j = 0; j < 5; ++j) acc[i][j] = (f32x4){0.f, 0.f, 0.f, 0.f};

  for (int ch = 0; ch < 7; ++ch) {
    __syncthreads();
    for (int it = tid; it < 768; it += 256) {
      int xl = it / 12, uvL = it % 12;
      int uv = ch * 12 + uvL;
      s16x8 hv = {0, 0, 0, 0, 0, 0, 0, 0}, lv = {0, 0, 0, 0, 0, 0, 0, 0};
      if (uv < 81) {
        int u = uv / 9, v = uv % 9;
        int ys = y + (4 - u) * dd;
        int xs = xl + (4 - v) * dd;
        if (ys >= 0 && ys < 64 && xs >= 0 && xs < 64) {
          const float* fp = feat + (size_t)uv * SAS + (size_t)(ys + 1) * SRS + (size_t)(xs + 1) * 16;
          float mv = mask[uv * 4096 + y * 64 + xl];
#pragma unroll
          for (int j = 0; j < 8; ++j) {
            float f = fp[j] * mv;
            unsigned short h = f2b(f);
            hv[j] = h;
            lv[j] = f2b(f - b2f(h));
          }
        }
      }
      *(s16x8*)&Ah[xl * 96 + uvL * 8] = hv;
      *(s16x8*)&Al[xl * 96 + uvL * 8] = lv;
    }
    __syncthreads();
#pragma unroll
    for (int kb = 0; kb < 3; ++kb) {
      int ka = kb * 32 + lq * 8;
      s16x8 a0h = *(const s16x8*)&Ah[(wm * 32 + lr) * 96 + ka];
      s16x8 a0l = *(const s16x8*)&Al[(wm * 32 + lr) * 96 + ka];
      s16x8 a1h = *(const s16x8*)&Ah[(wm * 32 + 16 + lr) * 96 + ka];
      s16x8 a1l = *(const s16x8*)&Al[(wm * 32 + 16 + lr) * 96 + ka];
      int kg = ch * 96 + ka;
#pragma unroll
      for (int nf = 0; nf < 5; ++nf) {
        int n = wn * 80 + nf * 16 + lr;
        s16x8 bh = *(const s16x8*)&ABH[(size_t)n * 672 + kg];
        s16x8 bl = *(const s16x8*)&ABL[(size_t)n * 672 + kg];
        acc[0][nf] = __builtin_amdgcn_mfma_f32_16x16x32_bf16(a0h, bh, acc[0][nf], 0, 0, 0);
        acc[0][nf] = __builtin_amdgcn_mfma_f32_16x16x32_bf16(a0h, bl, acc[0][nf], 0, 0, 0);
        acc[0][nf] = __builtin_amdgcn_mfma_f32_16x16x32_bf16(a0l, bh, acc[0][nf], 0, 0, 0);
        acc[1][nf] = __builtin_amdgcn_mfma_f32_16x16x32_bf16(a1h, bh, acc[1][nf], 0, 0, 0);
        acc[1][nf] = __builtin_amdgcn_mfma_f32_16x16x32_bf16(a1h, bl, acc[1][nf], 0, 0, 0);
        acc[1][nf] = __builtin_amdgcn_mfma_f32_16x16x32_bf16(a1l, bh, acc[1][nf], 0, 0, 0);
      }
    }
  }
#pragma unroll
  for (int nf = 0; nf < 5; ++nf) {
    int n = wn * 80 + nf * 16 + lr;
    float g = sq_bn[n], b = sq_bn[160 + n], m = sq_bn[320 + n], vv = sq_bn[480 + n];
    float sc = g * rsqrtf(vv + EPSB), sh = b - m * sc;
#pragma unroll
    for (int mf = 0; mf < 2; ++mf) {
#pragma unroll
      for (int r = 0; r < 4; ++r) {
        int x = wm * 32 + mf * 16 + lq * 4 + r;
        float val = acc[mf][nf][r] * invm[y * 64 + x];
        val = val * sc + sh;
        val = lrelu_f(val);
        outPA[(size_t)(dI + 1) * PZS + (size_t)(y + 1) * PYS + (size_t)(x + 1) * 160 + n] = val;
      }
    }
  }
}

// ---------------- tower: 1-pass fp16 MFMA 3x3x3 conv 160->160 ----------------
// fp32 state in global; fp16 A (single plane in LDS) x fp16 W; fp32 accum.
template <bool LRELU>
__global__ __launch_bounds__(256, 3) void k_mconv(const float* __restrict__ in,
                                                  float* __restrict__ out,
                                                  const _Float16* __restrict__ wh,
                                                  const float* __restrict__ bnp) {
  __shared__ _Float16 Af[66 * 168];
  int zy = blockIdx.x;
  int z = zy / 64, y = zy % 64;
  int tid = threadIdx.x;
  int lane = tid & 63;
  int wave = tid >> 6;
  int wm = wave >> 1, wn = wave & 1;
  int lr = lane & 15;
  int lq = lane >> 4;

  f32x4 acc[2][5];
#pragma unroll
  for (int i = 0; i < 2; ++i)
#pragma unroll
    for (int j = 0; j < 5; ++j) acc[i][j] = (f32x4){0.f, 0.f, 0.f, 0.f};

  const _Float16* wbase = wh + (size_t)(wn * 80 + lr) * 160 + lq * 8;

#pragma unroll 1
  for (int dzy = 0; dzy < 9; ++dzy) {
    int dz = dzy / 3, dy = dzy % 3;
    const float* src = in + (size_t)(z + dz) * PZS + (size_t)(y + dy) * PYS;
    __syncthreads();
    for (int v = tid; v < 2640; v += 256) {
      float4 f = *(const float4*)&src[v * 4];
      int row = v / 40, col = (v % 40) * 4;
      h16x4 hv;
      hv[0] = (_Float16)f.x;
      hv[1] = (_Float16)f.y;
      hv[2] = (_Float16)f.z;
      hv[3] = (_Float16)f.w;
      *(h16x4*)&Af[row * 168 + col] = hv;
    }
    __syncthreads();

#pragma unroll 1
    for (int dx = 0; dx < 3; ++dx) {
      const _Float16* wt = wbase + (size_t)(dzy * 3 + dx) * 25600;
      h16x8 bA[5], bB[5];
#pragma unroll
      for (int nf = 0; nf < 5; ++nf)
        bA[nf] = *(const h16x8*)&wt[(size_t)nf * 16 * 160];

      auto step = [&](int ks, h16x8 (&cur)[5], h16x8 (&nxt)[5], bool pre) {
        if (pre) {
#pragma unroll
          for (int nf = 0; nf < 5; ++nf)
            nxt[nf] = *(const h16x8*)&wt[(size_t)nf * 16 * 160 + (ks + 1) * 32];
        }
        int r0 = (wm * 32 + lr + dx) * 168 + ks * 32 + lq * 8;
        int r1 = r0 + 16 * 168;
        h16x8 a0 = *(const h16x8*)&Af[r0];
        h16x8 a1 = *(const h16x8*)&Af[r1];
#pragma unroll
        for (int nf = 0; nf < 5; ++nf) {
          acc[0][nf] = __builtin_amdgcn_mfma_f32_16x16x32_f16(a0, cur[nf], acc[0][nf], 0, 0, 0);
          acc[1][nf] = __builtin_amdgcn_mfma_f32_16x16x32_f16(a1, cur[nf], acc[1][nf], 0, 0, 0);
        }
      };
      step(0, bA, bB, true);
      step(1, bB, bA, true);
      step(2, bA, bB, true);
      step(3, bB, bA, true);
      step(4, bA, bB, false);
    }
  }
#pragma unroll
  for (int nf = 0; nf < 5; ++nf) {
    int n = wn * 80 + nf * 16 + lr;
    float sc = bnp[n] * rsqrtf(bnp[480 + n] + EPSB);
    float sh = bnp[160 + n] - bnp[320 + n] * sc;
#pragma unroll
    for (int mf = 0; mf < 2; ++mf) {
#pragma unroll
      for (int r = 0; r < 4; ++r) {
        int m = wm * 32 + mf * 16 + lq * 4 + r;
        float val = acc[mf][nf][r] * sc + sh;
        if (LRELU) val = lrelu_f(val);
        out[(size_t)(z + 1) * PZS + (size_t)(y + 1) * PYS + (size_t)(m + 1) * 160 + n] = val;
      }
    }
  }
}

// ---------------- c4: 160 -> 1 conv (fp32) ----------------
__global__ __launch_bounds__(256) void k_c4(const float* __restrict__ in,
                                            const float* __restrict__ w,
                                            float* __restrict__ score) {
  __shared__ float L[66 * 169];
  __shared__ float red[256];
  int zy = blockIdx.x;
  int z = zy / 64, y = zy % 64;
  int tid = threadIdx.x;
  int x = tid & 63, q = tid >> 6;
  float acc = 0.f;
  for (int dzy = 0; dzy < 9; ++dzy) {
    int dz = dzy / 3, dy = dzy % 3;
    const float* src = in + (size_t)(z + dz) * PZS + (size_t)(y + dy) * PYS;
    __syncthreads();
    for (int v = tid; v < 10560; v += 256) {
      int row = v / 160, col = v % 160;
      L[row * 169 + col] = src[v];
    }
    __syncthreads();
#pragma unroll 1
    for (int dx = 0; dx < 3; ++dx) {
      int t = dzy * 3 + dx;
      for (int ci = q * 40; ci < q * 40 + 40; ++ci)
        acc += L[(x + dx) * 169 + ci] * w[ci * 27 + t];
    }
  }
  red[tid] = acc;
  __syncthreads();
  if (q == 0)
    score[z * 4096 + y * 64 + x] = red[x] + red[64 + x] + red[128 + x] + red[192 + x];
}

// ---------------- channel attention ----------------
__global__ __launch_bounds__(256) void k_mean1(const float* __restrict__ in,
                                               float* __restrict__ ymp) {
  int z = blockIdx.x, yg = blockIdx.y, xq = blockIdx.z;
  int c = threadIdx.x;
  if (c >= 160) return;
  float s = 0.f;
  for (int yy = 0; yy < 8; ++yy) {
    int y = yg * 8 + yy;
    for (int xl = 0; xl < 16; ++xl) {
      int x = xq * 16 + xl;
      s += in[(size_t)(z + 1) * PZS + (size_t)(y + 1) * PYS + (size_t)(x + 1) * 160 + c];
    }
  }
  ymp[((z * 8 + yg) * 4 + xq) * 160 + c] = s;
}

__global__ __launch_bounds__(256) void k_mean2(const float* __restrict__ ymp,
                                               float* __restrict__ ym) {
  int idx = blockIdx.x * 256 + threadIdx.x;
  if (idx >= 1440) return;
  int c = idx / 9, z = idx % 9;
  float s = 0.f;
  for (int p = 0; p < 32; ++p) s += ymp[(z * 32 + p) * 160 + c];
  ym[idx] = s * (1.f / 4096.f);
}

__global__ __launch_bounds__(256) void k_ca(const float* __restrict__ ym,
                                            const float* __restrict__ w1,
                                            const float* __restrict__ b1,
                                            const float* __restrict__ bn1,
                                            const float* __restrict__ w2,
                                            const float* __restrict__ b2,
                                            const float* __restrict__ bn2,
                                            float* __restrict__ y2) {
  __shared__ float yml[1440];
  __shared__ float yy[90];
  for (int i = threadIdx.x; i < 1440; i += 256) yml[i] = ym[i];
  __syncthreads();
  if (threadIdx.x < 90) {
    int c = threadIdx.x / 9, z = threadIdx.x % 9;
    float acc = b1[c];
    for (int ci = 0; ci < 160; ++ci) acc += w1[c * 160 + ci] * yml[ci * 9 + z];
    float g = bn1[c], b = bn1[10 + c], m = bn1[20 + c], vv = bn1[30 + c];
    acc = (acc - m) * (g * rsqrtf(vv + EPSB)) + b;
    yy[threadIdx.x] = lrelu_f(acc);
  }
  __syncthreads();
  for (int i = threadIdx.x; i < 1440; i += 256) {
    int c = i / 9, z = i % 9;
    float acc = b2[c];
#pragma unroll
    for (int k = 0; k < 10; ++k) acc += w2[c * 10 + k] * yy[k * 9 + z];
    float g = bn2[c], b = bn2[160 + c], m = bn2[320 + c], vv = bn2[480 + c];
    acc = (acc - m) * (g * rsqrtf(vv + EPSB)) + b;
    y2[i] = 1.f / (1.f + expf(-acc));
  }
}

__global__ __launch_bounds__(256) void k_sadd(float* __restrict__ buf,
                                              const float* __restrict__ t,
                                              const float* __restrict__ y2) {
  int i = blockIdx.x * 256 + threadIdx.x;
  int p = i / 160, c = i % 160;
  int z = p >> 12, r = p & 4095;
  int y = r >> 6, x = r & 63;
  size_t a = (size_t)(z + 1) * PZS + (size_t)(y + 1) * PYS + (size_t)(x + 1) * 160 + c;
  buf[a] += t[a] * y2[c * 9 + z];
}

// ---------------- softmax + expectation ----------------
__global__ __launch_bounds__(256) void k_out(const float* __restrict__ score,
                                             float* __restrict__ out) {
  int p = blockIdx.x * 256 + threadIdx.x;
  float v[9];
  float mx = -1e30f;
#pragma unroll
  for (int z = 0; z < 9; ++z) {
    v[z] = score[z * 4096 + p];
    mx = fmaxf(mx, v[z]);
  }
  float s = 0.f, r = 0.f;
#pragma unroll
  for (int z = 0; z < 9; ++z) {
    float e = expf(v[z] - mx);
    s += e;
    r += e * (float)(z - 4);
  }
  out[p] = r / s;
}

// ---------------- launch ----------------
extern "C" void kernel_launch(void* const* d_in, const int* in_sizes, int n_in,
                              void* d_out, int out_size, void* d_ws, size_t ws_size,
                              hipStream_t stream) {
  const float* X      = (const float*)d_in[0];
  const float* disp   = (const float*)d_in[1];
  const float* if_w0  = (const float*)d_in[2];
  const float* if_bn0 = (const float*)d_in[3];
  const float* resb_w = (const float*)d_in[4];
  const float* resb_b = (const float*)d_in[5];
  const float* resb_bn= (const float*)d_in[6];
  const float* if_w1  = (const float*)d_in[7];
  const float* if_bn1 = (const float*)d_in[8];
  const float* if_w2  = (const float*)d_in[9];
  const float* if_bn2 = (const float*)d_in[10];
  const float* last_w = (const float*)d_in[11];
  const float* fuse_w = (const float*)d_in[12];
  const float* sq_w   = (const float*)d_in[13];
  const float* sq_bn  = (const float*)d_in[14];
  const float* c1_w   = (const float*)d_in[15];
  const float* c1_bn  = (const float*)d_in[16];
  const float* c2_w   = (const float*)d_in[17];
  const float* c2_bn  = (const float*)d_in[18];
  const float* c3_w   = (const float*)d_in[19];
  const float* c3_bn  = (const float*)d_in[20];
  const float* c4_w   = (const float*)d_in[21];
  const float* r3_w   = (const float*)d_in[22];
  const float* r3_bn  = (const float*)d_in[23];
  const float* ca_w1  = (const float*)d_in[24];
  const float* ca_b1  = (const float*)d_in[25];
  const float* ca_bn1 = (const float*)d_in[26];
  const float* ca_w2  = (const float*)d_in[27];
  const float* ca_b2  = (const float*)d_in[28];
  const float* ca_bn2 = (const float*)d_in[29];

  float* ws   = (float*)d_ws;
  float* SA   = ws + OFF_SA;
  float* SB   = ws + OFF_SB;
  float* PC   = ws;               // overlays SA/SB (dead after costsq)
  float* MASK = ws + OFF_MASK;
  float* INVM = ws + OFF_INVM;
  float* SC   = ws + OFF_SC;
  float* YM   = ws + OFF_YM;
  float* Y2   = ws + OFF_Y2;
  float* YMP  = ws + OFF_YMP;
  float* PA   = ws + OFF_PA;
  float* PB   = ws + OFF_PB;
  unsigned short* U   = (unsigned short*)d_ws;
  _Float16* WH        = (_Float16*)(U + UOFF_WH);
  unsigned short* WSH = U + UOFF_WSH;
  unsigned short* WSL = U + UOFF_WSL;
  unsigned short* ABH = U + UOFF_ABH;
  unsigned short* ABL = U + UOFF_ABL;

  hipMemsetAsync(SA, 0, SVOL * 4, stream);
  hipMemsetAsync(SB, 0, SVOL * 4, stream);
  hipMemsetAsync(PA, 0, PVOL * 4, stream);
  hipMemsetAsync(PB, 0, PVOL * 4, stream);

  k_wt7<<<dim3(100, 7), 256, 0, stream>>>(c1_w, c2_w, r3_w, c3_w, WH);
  k_wslice<<<19, 256, 0, stream>>>(resb_w, if_w1, if_w2, last_w, WSH, WSL);
  k_A<<<672, 192, 0, stream>>>(sq_w, fuse_w, ABH, ABL);
  k_mask<<<16, 256, 0, stream>>>(X, disp, MASK, INVM);

  k_if0<<<dim3(81, 16), 256, 0, stream>>>(X, if_w0, if_bn0, SA);
  for (int i = 0; i < 8; ++i) {
    k_cs<true, true, false, 16><<<dim3(81, 8), 256, 0, stream>>>(
        SA, SB, WSH + (size_t)(2 * i) * 2560, WSL + (size_t)(2 * i) * 2560,
        resb_b + i * 32, resb_bn + i * 128);
    k_cs<true, false, true, 16><<<dim3(81, 8), 256, 0, stream>>>(
        SB, SA, WSH + (size_t)(2 * i + 1) * 2560, WSL + (size_t)(2 * i + 1) * 2560,
        resb_b + i * 32 + 16, resb_bn + i * 128 + 64);
  }
  k_cs<true, true, false, 16><<<dim3(81, 8), 256, 0, stream>>>(
      SA, SB, WSH + 16 * 2560, WSL + 16 * 2560, nullptr, if_bn1);
  k_cs<true, true, false, 8><<<dim3(81, 8), 256, 0, stream>>>(
      SB, SA, WSH + 17 * 2560, WSL + 17 * 2560, nullptr, if_bn2);
  k_cs<false, false, false, 8><<<dim3(81, 8), 256, 0, stream>>>(
      SA, SB, WSH + 18 * 2560, WSL + 18 * 2560, nullptr, nullptr);

  k_costsq<<<dim3(9, 64), 256, 0, stream>>>(SB, MASK, INVM, ABH, ABL, sq_bn, PA);
  hipMemsetAsync(PC, 0, PVOL * 4, stream);  // SA/SB dead; PC borders must be zero

  k_mconv<true><<<576, 256, 0, stream>>>(PA, PB, WH + 0ull * 691200, c1_bn);
  k_mconv<true><<<576, 256, 0, stream>>>(PB, PA, WH + 1ull * 691200, c2_bn);
  for (int i = 0; i < 2; ++i) {
    k_mconv<true><<<576, 256, 0, stream>>>(PA, PB, WH + (size_t)(2 + 2 * i) * 691200,
                                           r3_bn + i * 1280);
    k_mconv<false><<<576, 256, 0, stream>>>(PB, PC, WH + (size_t)(3 + 2 * i) * 691200,
                                            r3_bn + i * 1280 + 640);
    k_mean1<<<dim3(9, 8, 4), 256, 0, stream>>>(PC, YMP);
    k_mean2<<<6, 256, 0, stream>>>(YMP, YM);
    k_ca<<<1, 256, 0, stream>>>(YM, ca_w1 + i * 1600, ca_b1 + i * 10, ca_bn1 + i * 40,
                                ca_w2 + i * 1600, ca_b2 + i * 160, ca_bn2 + i * 640, Y2);
    k_sadd<<<23040, 256, 0, stream>>>(PA, PC, Y2);
  }
  k_mconv<true><<<576, 256, 0, stream>>>(PA, PB, WH + 6ull * 691200, c3_bn);
  k_c4<<<576, 256, 0, stream>>>(PB, c4_w, SC);
  k_out<<<16, 256, 0, stream>>>(SC, (float*)d_out);
}